// Round 1
// baseline (1189.151 us; speedup 1.0000x reference)
//
#include <hip/hip_runtime.h>

#define NP 2048
#define BATCH 8
#define KNN 40
#define EPSF 1e-6f
#define BNEPS 1e-5f

__device__ __forceinline__ unsigned ordf(float v){
  unsigned u = __float_as_uint(v);
  return (u & 0x80000000u) ? ~u : (u | 0x80000000u);
}

__device__ __forceinline__ unsigned long long wmax64(unsigned long long v){
  #pragma unroll
  for (int s = 32; s > 0; s >>= 1){
    unsigned long long o = __shfl_xor(v, s, 64);
    v = (o > v) ? o : v;
  }
  return v;
}

// ---------------- KNN: exact top-40 (nearest incl. self), tie -> lowest index ----------
__global__ __launch_bounds__(256) void knn_kernel(const float* __restrict__ x, int* __restrict__ idx){
  __shared__ float sx0[NP], sx1[NP], sx2[NP], sxx[NP];
  int tid = threadIdx.x;
  int w = tid >> 6, lane = tid & 63;
  int row = blockIdx.x * 4 + w;
  int b = row >> 11, i = row & 2047;
  const float* xb = x + b * 3 * NP;
  for (int t = tid; t < NP; t += 256){ sx0[t] = xb[t]; sx1[t] = xb[NP + t]; sx2[t] = xb[2*NP + t]; }
  __syncthreads();
  for (int t = tid; t < NP; t += 256){
    float a = sx0[t], c = sx1[t], d = sx2[t];
    sxx[t] = __fadd_rn(__fadd_rn(__fmul_rn(a,a), __fmul_rn(c,c)), __fmul_rn(d,d));
  }
  __syncthreads();
  float xi0 = sx0[i], xi1 = sx1[i], xi2 = sx2[i], xxi = sxx[i];
  float nd[32];
  unsigned long long s0 = 0, s1 = 0, s2 = 0, s3 = 0;
  #pragma unroll
  for (int m = 0; m < 32; m++){
    int j = m * 64 + lane;
    float dot = __fadd_rn(__fadd_rn(__fmul_rn(xi0, sx0[j]), __fmul_rn(xi1, sx1[j])), __fmul_rn(xi2, sx2[j]));
    float v = __fsub_rn(__fsub_rn(-xxi, __fmul_rn(-2.f, dot)), sxx[j]);
    nd[m] = v;
    unsigned long long pk = ((unsigned long long)ordf(v) << 32) | (unsigned)(2047 - j);
    if (pk > s3){
      if (pk > s2){ s3 = s2; if (pk > s1){ s2 = s1; if (pk > s0){ s1 = s0; s0 = pk; } else s1 = pk; } else s2 = pk; }
      else s3 = pk;
    }
  }
  unsigned long long lastPop = ~0ull;
  int* outp = idx + row * KNN;
  for (int kk = 0; kk < KNN; kk++){
    unsigned long long g = wmax64(s0);
    if (s0 == g){
      outp[kk] = 2047 - (int)(g & 0xffffffffu);
      lastPop = g;
      s0 = s1; s1 = s2; s2 = s3; s3 = 0;
      if (s0 == 0){
        unsigned long long best = 0;
        #pragma unroll
        for (int m = 0; m < 32; m++){
          int j = m * 64 + lane;
          unsigned long long pk = ((unsigned long long)ordf(nd[m]) << 32) | (unsigned)(2047 - j);
          if (pk < lastPop && pk > best) best = pk;
        }
        s0 = best;
      }
    }
  }
}

// ------------- graph-feature layer: stats pass (p-norm sums per channel, 21 ch) --------
__global__ __launch_bounds__(256) void gf_stats(const float* __restrict__ x, const int* __restrict__ idx,
                                                const float* __restrict__ Wf, double* __restrict__ sums){
  int tid0 = blockIdx.x * 256 + threadIdx.x;
  float s[21], q[21];
  #pragma unroll
  for (int o = 0; o < 21; o++){ s[o] = 0.f; q[o] = 0.f; }
  for (int pix = tid0; pix < BATCH * NP * KNN; pix += 256 * 256){
    int rem = pix / KNN;
    int n = rem & 2047, b = rem >> 11;
    int j = idx[pix];
    const float* xb = x + b * 3 * NP;
    float c0 = xb[n], c1 = xb[NP + n], c2 = xb[2*NP + n];
    float a0 = xb[j], a1 = xb[NP + j], a2 = xb[2*NP + j];
    float r0 = a0 - c0, r1 = a1 - c1, r2 = a2 - c2;
    float g0 = a1*c2 - a2*c1, g1 = a2*c0 - a0*c2, g2 = a0*c1 - a1*c0;
    #pragma unroll
    for (int o = 0; o < 21; o++){
      float w0 = Wf[o*3], w1 = Wf[o*3+1], w2 = Wf[o*3+2];
      float p0 = w0*r0 + w1*c0 + w2*g0;
      float p1 = w0*r1 + w1*c1 + w2*g1;
      float p2 = w0*r2 + w1*c2 + w2*g2;
      float nm = sqrtf(p0*p0 + p1*p1 + p2*p2) + EPSF;
      s[o] += nm; q[o] += nm * nm;
    }
  }
  __shared__ float bs[4][42];
  int w = threadIdx.x >> 6;
  #pragma unroll
  for (int o = 0; o < 21; o++){
    float a = s[o], bb = q[o];
    #pragma unroll
    for (int st = 1; st < 64; st <<= 1){ a += __shfl_xor(a, st, 64); bb += __shfl_xor(bb, st, 64); }
    if ((threadIdx.x & 63) == 0){ bs[w][o] = a; bs[w][21 + o] = bb; }
  }
  __syncthreads();
  if (threadIdx.x < 42){
    float tot = bs[0][threadIdx.x] + bs[1][threadIdx.x] + bs[2][threadIdx.x] + bs[3][threadIdx.x];
    int o = threadIdx.x % 21, sq = threadIdx.x / 21;
    atomicAdd(&sums[2*o + sq], (double)tot);
  }
}

// -------- graph-feature layer: apply bn+lrelu, then max-pool over K (fused) ------------
__global__ __launch_bounds__(256) void gf_applypool(const float* __restrict__ x, const int* __restrict__ idx,
    const float* __restrict__ Wf, const float* __restrict__ Wd, const float* __restrict__ Wg,
    const float* __restrict__ mi, float* __restrict__ h1){
  int w = threadIdx.x >> 6, lane = threadIdx.x & 63;
  int pix = blockIdx.x * 4 + w;
  int n = pix & 2047, b = pix >> 11;
  const float* xb = x + b * 3 * NP;
  float c0 = xb[n], c1 = xb[NP + n], c2 = xb[2*NP + n];
  int j = (lane < KNN) ? idx[pix * KNN + lane] : n;
  float a0 = xb[j], a1 = xb[NP + j], a2 = xb[2*NP + j];
  float r0 = a0 - c0, r1 = a1 - c1, r2 = a2 - c2;
  float g0 = a1*c2 - a2*c1, g1 = a2*c0 - a0*c2, g2 = a0*c1 - a1*c0;
  float h[21][3];
  #pragma unroll
  for (int o = 0; o < 21; o++){
    float w0 = Wf[o*3], w1 = Wf[o*3+1], w2 = Wf[o*3+2];
    float p0 = w0*r0 + w1*c0 + w2*g0;
    float p1 = w0*r1 + w1*c1 + w2*g1;
    float p2 = w0*r2 + w1*c2 + w2*g2;
    float nm = sqrtf(p0*p0 + p1*p1 + p2*p2) + EPSF;
    float f = (nm - mi[2*o]) * mi[2*o+1] / nm;
    p0 *= f; p1 *= f; p2 *= f;
    float v0 = Wd[o*3], v1 = Wd[o*3+1], v2 = Wd[o*3+2];
    float d0 = v0*r0 + v1*c0 + v2*g0;
    float d1 = v0*r1 + v1*c1 + v2*g1;
    float d2 = v0*r2 + v1*c2 + v2*g2;
    float dot = p0*d0 + p1*d1 + p2*d2;
    float dsq = d0*d0 + d1*d1 + d2*d2;
    float t = dot / (dsq + EPSF);
    h[o][0] = (dot >= 0.f) ? p0 : fmaf(-t, d0, p0);
    h[o][1] = (dot >= 0.f) ? p1 : fmaf(-t, d1, p1);
    h[o][2] = (dot >= 0.f) ? p2 : fmaf(-t, d2, p2);
  }
  #pragma unroll
  for (int o = 0; o < 21; o++){
    float q0 = 0.f, q1 = 0.f, q2 = 0.f;
    #pragma unroll
    for (int c = 0; c < 21; c++){
      float wg = Wg[o*21 + c];
      q0 = fmaf(wg, h[c][0], q0); q1 = fmaf(wg, h[c][1], q1); q2 = fmaf(wg, h[c][2], q2);
    }
    float dp = q0*h[o][0] + q1*h[o][1] + q2*h[o][2];
    unsigned long long pk = (lane < KNN) ? ((unsigned long long)ordf(dp) << 32) | (unsigned)(63 - lane) : 0ull;
    unsigned long long g = wmax64(pk);
    int wl = 63 - (int)(g & 0xffffffffu);
    float o0 = __shfl(h[o][0], wl, 64);
    float o1 = __shfl(h[o][1], wl, 64);
    float o2 = __shfl(h[o][2], wl, 64);
    if (lane == 0){
      float* dst = h1 + (size_t)((b*21 + o)*3) * NP + n;
      dst[0] = o0; dst[NP] = o1; dst[2*NP] = o2;
    }
  }
}

// ---------------- generic VN layer: stats + apply (thread per (b,n)) ------------------
template<int CIN>
__global__ __launch_bounds__(256) void layer_stats(const float* __restrict__ hin, const float* __restrict__ Wf,
                                                   double* __restrict__ sums, int Co, int oPerG){
  int tid = blockIdx.x * 256 + threadIdx.x;
  int n = tid & 2047, b = tid >> 11;
  int o0 = blockIdx.y * oPerG;
  int o1 = o0 + oPerG; if (o1 > Co) o1 = Co;
  float h[CIN*3];
  #pragma unroll
  for (int c = 0; c < CIN; c++){
    #pragma unroll
    for (int e = 0; e < 3; e++) h[c*3+e] = hin[(size_t)((b*CIN + c)*3 + e) * NP + n];
  }
  int lane = threadIdx.x & 63;
  for (int o = o0; o < o1; o++){
    float p0 = 0.f, p1 = 0.f, p2 = 0.f;
    #pragma unroll
    for (int c = 0; c < CIN; c++){
      float wv = Wf[o*CIN + c];
      p0 = fmaf(wv, h[c*3], p0); p1 = fmaf(wv, h[c*3+1], p1); p2 = fmaf(wv, h[c*3+2], p2);
    }
    float nm = sqrtf(p0*p0 + p1*p1 + p2*p2) + EPSF;
    float v1 = nm, v2 = nm * nm;
    #pragma unroll
    for (int st = 1; st < 64; st <<= 1){ v1 += __shfl_xor(v1, st, 64); v2 += __shfl_xor(v2, st, 64); }
    if (lane == 0){ atomicAdd(&sums[2*o], (double)v1); atomicAdd(&sums[2*o+1], (double)v2); }
  }
}

template<int CIN>
__global__ __launch_bounds__(256) void layer_apply(const float* __restrict__ hin, const float* __restrict__ Wf,
    const float* __restrict__ Wd, const float* __restrict__ mi, float* __restrict__ hout, int Co, int oPerG){
  int tid = blockIdx.x * 256 + threadIdx.x;
  int n = tid & 2047, b = tid >> 11;
  int o0 = blockIdx.y * oPerG;
  int o1 = o0 + oPerG; if (o1 > Co) o1 = Co;
  float h[CIN*3];
  #pragma unroll
  for (int c = 0; c < CIN; c++){
    #pragma unroll
    for (int e = 0; e < 3; e++) h[c*3+e] = hin[(size_t)((b*CIN + c)*3 + e) * NP + n];
  }
  for (int o = o0; o < o1; o++){
    float p0 = 0.f, p1 = 0.f, p2 = 0.f, d0 = 0.f, d1 = 0.f, d2 = 0.f;
    #pragma unroll
    for (int c = 0; c < CIN; c++){
      float wv = Wf[o*CIN + c], vv = Wd[o*CIN + c];
      p0 = fmaf(wv, h[c*3], p0); p1 = fmaf(wv, h[c*3+1], p1); p2 = fmaf(wv, h[c*3+2], p2);
      d0 = fmaf(vv, h[c*3], d0); d1 = fmaf(vv, h[c*3+1], d1); d2 = fmaf(vv, h[c*3+2], d2);
    }
    float nm = sqrtf(p0*p0 + p1*p1 + p2*p2) + EPSF;
    float f = (nm - mi[2*o]) * mi[2*o+1] / nm;
    p0 *= f; p1 *= f; p2 *= f;
    float dot = p0*d0 + p1*d1 + p2*d2;
    float dsq = d0*d0 + d1*d1 + d2*d2;
    float t = dot / (dsq + EPSF);
    float r0 = (dot >= 0.f) ? p0 : fmaf(-t, d0, p0);
    float r1 = (dot >= 0.f) ? p1 : fmaf(-t, d1, p1);
    float r2 = (dot >= 0.f) ? p2 : fmaf(-t, d2, p2);
    float* dst = hout + (size_t)((b*Co + o)*3) * NP + n;
    dst[0] = r0; dst[NP] = r1; dst[2*NP] = r2;
  }
}

__global__ void finalize_stats(const double* __restrict__ sums, float* __restrict__ mi, int Co, double invM){
  int o = blockIdx.x * 64 + threadIdx.x;
  if (o >= Co) return;
  double m = sums[2*o] * invM;
  double v = sums[2*o+1] * invM - m * m;
  if (v < 0.0) v = 0.0;
  mi[2*o] = (float)m;
  mi[2*o+1] = (float)(1.0 / sqrt(v + (double)BNEPS));
}

// ------------- pool over N: D = W_pool @ H per (b,e); dot; packed argmax ---------------
__global__ __launch_bounds__(256) void pool_gemm(const float* __restrict__ h4, const float* __restrict__ Wp,
                                                 unsigned long long* __restrict__ packed){
  int b = blockIdx.z, ot = blockIdx.y, nt = blockIdx.x;
  int o0 = ot * 64, n0 = nt * 64;
  __shared__ float sW[32][68];
  __shared__ float sH[32][64];
  int tid = threadIdx.x, tx = tid & 15, ty = tid >> 4;
  float dot[4][4];
  #pragma unroll
  for (int r = 0; r < 4; r++)
    #pragma unroll
    for (int q = 0; q < 4; q++) dot[r][q] = 0.f;
  for (int e = 0; e < 3; e++){
    float acc[4][4];
    #pragma unroll
    for (int r = 0; r < 4; r++)
      #pragma unroll
      for (int q = 0; q < 4; q++) acc[r][q] = 0.f;
    for (int c0 = 0; c0 < 341; c0 += 32){
      #pragma unroll
      for (int it = 0; it < 8; it++){
        int t = tid + it * 256;
        int i = t >> 5, kk = t & 31;
        int o = o0 + i, c = c0 + kk;
        sW[kk][i] = (o < 341 && c < 341) ? Wp[o*341 + c] : 0.f;
      }
      #pragma unroll
      for (int it = 0; it < 8; it++){
        int t = tid + it * 256;
        int kk = t >> 6, jj = t & 63;
        int c = c0 + kk;
        sH[kk][jj] = (c < 341) ? h4[(size_t)((b*341 + c)*3 + e) * NP + n0 + jj] : 0.f;
      }
      __syncthreads();
      #pragma unroll
      for (int kk = 0; kk < 32; kk++){
        float4 wv = *(const float4*)&sW[kk][ty*4];
        float4 hv = *(const float4*)&sH[kk][tx*4];
        float wa[4] = {wv.x, wv.y, wv.z, wv.w};
        float ha[4] = {hv.x, hv.y, hv.z, hv.w};
        #pragma unroll
        for (int r = 0; r < 4; r++)
          #pragma unroll
          for (int q = 0; q < 4; q++) acc[r][q] = fmaf(wa[r], ha[q], acc[r][q]);
      }
      __syncthreads();
    }
    #pragma unroll
    for (int r = 0; r < 4; r++){
      int o = o0 + ty*4 + r;
      if (o < 341){
        const float* hp = &h4[(size_t)((b*341 + o)*3 + e) * NP + n0 + tx*4];
        #pragma unroll
        for (int q = 0; q < 4; q++) dot[r][q] = fmaf(acc[r][q], hp[q], dot[r][q]);
      }
    }
  }
  __shared__ unsigned long long sRed[64][17];
  #pragma unroll
  for (int r = 0; r < 4; r++){
    unsigned long long best = 0;
    #pragma unroll
    for (int q = 0; q < 4; q++){
      int nn = n0 + tx*4 + q;
      unsigned long long pk = ((unsigned long long)ordf(dot[r][q]) << 32) | (unsigned)(2047 - nn);
      if (pk > best) best = pk;
    }
    sRed[ty*4 + r][tx] = best;
  }
  __syncthreads();
  if (tid < 64){
    unsigned long long best = 0;
    #pragma unroll
    for (int t2 = 0; t2 < 16; t2++){ unsigned long long v = sRed[tid][t2]; if (v > best) best = v; }
    int o = o0 + tid;
    if (o < 341) atomicMax(&packed[b*341 + o], best);
  }
}

__global__ void pool_gather(const unsigned long long* __restrict__ packed, const float* __restrict__ h4,
                            float* __restrict__ pooled){
  int t = blockIdx.x * 256 + threadIdx.x;
  if (t >= BATCH * 341) return;
  int n = 2047 - (int)(packed[t] & 0xffffffffu);
  pooled[t*3 + 0] = h4[(size_t)(t*3 + 0) * NP + n];
  pooled[t*3 + 1] = h4[(size_t)(t*3 + 1) * NP + n];
  pooled[t*3 + 2] = h4[(size_t)(t*3 + 2) * NP + n];
}

// -------- fully-connected VN layer (B=8 pixels, per-channel bn over B) -----------------
__global__ __launch_bounds__(64) void flayer(const float* __restrict__ in, const float* __restrict__ Wf,
    const float* __restrict__ Wd, float* __restrict__ out, int Cin, int Co){
  int o = blockIdx.x, lane = threadIdx.x;
  float pv[24], dv[24];
  #pragma unroll
  for (int be = 0; be < 24; be++){ pv[be] = 0.f; dv[be] = 0.f; }
  for (int c = lane; c < Cin; c += 64){
    float wf = Wf[o*Cin + c], wd = Wd[o*Cin + c];
    #pragma unroll
    for (int bb = 0; bb < 8; bb++){
      #pragma unroll
      for (int e = 0; e < 3; e++){
        float hv = in[(bb*Cin + c)*3 + e];
        pv[bb*3+e] = fmaf(wf, hv, pv[bb*3+e]);
        dv[bb*3+e] = fmaf(wd, hv, dv[bb*3+e]);
      }
    }
  }
  #pragma unroll
  for (int be = 0; be < 24; be++){
    #pragma unroll
    for (int st = 1; st < 64; st <<= 1){
      pv[be] += __shfl_xor(pv[be], st, 64);
      dv[be] += __shfl_xor(dv[be], st, 64);
    }
  }
  float nm[8], dotb[8], dsqb[8];
  float mean = 0.f;
  #pragma unroll
  for (int bb = 0; bb < 8; bb++){
    nm[bb] = sqrtf(pv[bb*3]*pv[bb*3] + pv[bb*3+1]*pv[bb*3+1] + pv[bb*3+2]*pv[bb*3+2]) + EPSF;
    mean += nm[bb];
  }
  mean *= 0.125f;
  float var = 0.f;
  #pragma unroll
  for (int bb = 0; bb < 8; bb++){ float dvv = nm[bb] - mean; var += dvv * dvv; }
  var *= 0.125f;
  float istd = 1.f / sqrtf(var + BNEPS);
  #pragma unroll
  for (int bb = 0; bb < 8; bb++){
    float f = (nm[bb] - mean) * istd / nm[bb];
    dotb[bb] = f * (pv[bb*3]*dv[bb*3] + pv[bb*3+1]*dv[bb*3+1] + pv[bb*3+2]*dv[bb*3+2]);
    dsqb[bb] = dv[bb*3]*dv[bb*3] + dv[bb*3+1]*dv[bb*3+1] + dv[bb*3+2]*dv[bb*3+2];
  }
  #pragma unroll
  for (int be = 0; be < 24; be++){
    if (lane == be){
      int bb = be / 3;
      float f = (nm[bb] - mean) * istd / nm[bb];
      float pe = pv[be] * f;
      float t = dotb[bb] / (dsqb[bb] + EPSF);
      float res = (dotb[bb] >= 0.f) ? pe : fmaf(-t, dv[be], pe);
      out[(bb*Co + o)*3 + (be % 3)] = res;
    }
  }
}

__global__ void final_lin(const float* __restrict__ in, const float* __restrict__ W, float* __restrict__ out){
  int t = threadIdx.x;
  if (t >= 72) return;
  int b = t / 9, o = (t % 9) / 3, e = t % 3;
  float s = 0.f;
  for (int c = 0; c < 85; c++) s = fmaf(W[o*85 + c], in[(b*85 + c)*3 + e], s);
  out[t] = s;
}

// --------------------------------- launcher -------------------------------------------
extern "C" void kernel_launch(void* const* d_in, const int* in_sizes, int n_in,
                              void* d_out, int out_size, void* d_ws, size_t ws_size,
                              hipStream_t stream){
  const float* x   = (const float*)d_in[0];
  const float* Wpf = (const float*)d_in[1];
  const float* Wpd = (const float*)d_in[2];
  const float* Wg  = (const float*)d_in[3];
  const float* W1f = (const float*)d_in[4];
  const float* W1d = (const float*)d_in[5];
  const float* W2f = (const float*)d_in[6];
  const float* W2d = (const float*)d_in[7];
  const float* W3f = (const float*)d_in[8];
  const float* W3d = (const float*)d_in[9];
  const float* Wpool = (const float*)d_in[10];
  const float* Wf1f = (const float*)d_in[11];
  const float* Wf1d = (const float*)d_in[12];
  const float* Wf2f = (const float*)d_in[13];
  const float* Wf2d = (const float*)d_in[14];
  const float* Wf3  = (const float*)d_in[15];
  float* out = (float*)d_out;

  char* ws = (char*)d_ws;
  size_t off = 0;
  int*   idx = (int*)(ws + off);              off += (size_t)BATCH*NP*KNN*4;          // 2,621,440
  float* h1  = (float*)(ws + off);            off += (size_t)BATCH*21*3*NP*4;         // 4,128,768
  float* h2  = (float*)(ws + off);            off += (size_t)BATCH*21*3*NP*4;
  float* h3  = (float*)(ws + off);            off += (size_t)BATCH*42*3*NP*4;
  float* h4  = (float*)(ws + off);            off += (size_t)BATCH*341*3*NP*4;        // 67 MB
  char*  zbase = ws + off;
  double* sums_gf = (double*)(ws + off);      off += 8192;
  double* sums_l1 = (double*)(ws + off);      off += 8192;
  double* sums_l2 = (double*)(ws + off);      off += 8192;
  double* sums_l3 = (double*)(ws + off);      off += 8192;
  unsigned long long* packed = (unsigned long long*)(ws + off); off += 24576;
  size_t zbytes = (ws + off) - zbase;
  float* mi_gf = (float*)(ws + off);          off += 1024;
  float* mi_l1 = (float*)(ws + off);          off += 1024;
  float* mi_l2 = (float*)(ws + off);          off += 1024;
  float* mi_l3 = (float*)(ws + off);          off += 4096;
  float* pooled = (float*)(ws + off);         off += (size_t)BATCH*341*3*4 + 32;
  float* h5 = (float*)(ws + off);             off += (size_t)BATCH*170*3*4 + 32;
  float* h6 = (float*)(ws + off);             off += (size_t)BATCH*85*3*4 + 32;

  hipMemsetAsync(zbase, 0, zbytes, stream);

  knn_kernel<<<BATCH*NP/4, 256, 0, stream>>>(x, idx);

  gf_stats<<<256, 256, 0, stream>>>(x, idx, Wpf, sums_gf);
  finalize_stats<<<1, 64, 0, stream>>>(sums_gf, mi_gf, 21, 1.0 / (double)(BATCH*NP*KNN));
  gf_applypool<<<BATCH*NP/4, 256, 0, stream>>>(x, idx, Wpf, Wpd, Wg, mi_gf, h1);

  layer_stats<21><<<dim3(64,1), 256, 0, stream>>>(h1, W1f, sums_l1, 21, 21);
  finalize_stats<<<1, 64, 0, stream>>>(sums_l1, mi_l1, 21, 1.0 / (double)(BATCH*NP));
  layer_apply<21><<<dim3(64,1), 256, 0, stream>>>(h1, W1f, W1d, mi_l1, h2, 21, 21);

  layer_stats<21><<<dim3(64,1), 256, 0, stream>>>(h2, W2f, sums_l2, 42, 42);
  finalize_stats<<<1, 64, 0, stream>>>(sums_l2, mi_l2, 42, 1.0 / (double)(BATCH*NP));
  layer_apply<21><<<dim3(64,1), 256, 0, stream>>>(h2, W2f, W2d, mi_l2, h3, 42, 42);

  layer_stats<42><<<dim3(64,4), 256, 0, stream>>>(h3, W3f, sums_l3, 341, 86);
  finalize_stats<<<6, 64, 0, stream>>>(sums_l3, mi_l3, 341, 1.0 / (double)(BATCH*NP));
  layer_apply<42><<<dim3(64,4), 256, 0, stream>>>(h3, W3f, W3d, mi_l3, h4, 341, 86);

  pool_gemm<<<dim3(32, 6, BATCH), 256, 0, stream>>>(h4, Wpool, packed);
  pool_gather<<<(BATCH*341 + 255)/256, 256, 0, stream>>>(packed, h4, pooled);

  flayer<<<170, 64, 0, stream>>>(pooled, Wf1f, Wf1d, h5, 341, 170);
  flayer<<<85, 64, 0, stream>>>(h5, Wf2f, Wf2d, h6, 170, 85);
  final_lin<<<1, 128, 0, stream>>>(h6, Wf3, out);
}

// Round 2
// 1074.587 us; speedup vs baseline: 1.1066x; 1.1066x over previous
//
#include <hip/hip_runtime.h>

#define NP 2048
#define BATCH 8
#define KNN 40
#define EPSF 1e-6f
#define BNEPS 1e-5f

__device__ __forceinline__ unsigned ordf(float v){
  unsigned u = __float_as_uint(v);
  return (u & 0x80000000u) ? ~u : (u | 0x80000000u);
}

__device__ __forceinline__ unsigned long long wmax64(unsigned long long v){
  #pragma unroll
  for (int s = 32; s > 0; s >>= 1){
    unsigned long long o = __shfl_xor(v, s, 64);
    v = (o > v) ? o : v;
  }
  return v;
}

// ---------------- KNN: exact top-40 (nearest incl. self), tie -> lowest index ----------
__global__ __launch_bounds__(256) void knn_kernel(const float* __restrict__ x, int* __restrict__ idx){
  __shared__ float sx0[NP], sx1[NP], sx2[NP], sxx[NP];
  int tid = threadIdx.x;
  int w = tid >> 6, lane = tid & 63;
  int row = blockIdx.x * 4 + w;
  int b = row >> 11, i = row & 2047;
  const float* xb = x + b * 3 * NP;
  for (int t = tid; t < NP; t += 256){ sx0[t] = xb[t]; sx1[t] = xb[NP + t]; sx2[t] = xb[2*NP + t]; }
  __syncthreads();
  for (int t = tid; t < NP; t += 256){
    float a = sx0[t], c = sx1[t], d = sx2[t];
    sxx[t] = __fadd_rn(__fadd_rn(__fmul_rn(a,a), __fmul_rn(c,c)), __fmul_rn(d,d));
  }
  __syncthreads();
  float xi0 = sx0[i], xi1 = sx1[i], xi2 = sx2[i], xxi = sxx[i];
  float nd[32];
  unsigned long long s0 = 0, s1 = 0, s2 = 0, s3 = 0;
  #pragma unroll
  for (int m = 0; m < 32; m++){
    int j = m * 64 + lane;
    float dot = __fadd_rn(__fadd_rn(__fmul_rn(xi0, sx0[j]), __fmul_rn(xi1, sx1[j])), __fmul_rn(xi2, sx2[j]));
    float v = __fsub_rn(__fsub_rn(-xxi, __fmul_rn(-2.f, dot)), sxx[j]);
    nd[m] = v;
    unsigned long long pk = ((unsigned long long)ordf(v) << 32) | (unsigned)(2047 - j);
    if (pk > s3){
      if (pk > s2){ s3 = s2; if (pk > s1){ s2 = s1; if (pk > s0){ s1 = s0; s0 = pk; } else s1 = pk; } else s2 = pk; }
      else s3 = pk;
    }
  }
  unsigned long long lastPop = ~0ull;
  int* outp = idx + row * KNN;
  for (int kk = 0; kk < KNN; kk++){
    unsigned long long g = wmax64(s0);
    if (s0 == g){
      outp[kk] = 2047 - (int)(g & 0xffffffffu);
      lastPop = g;
      s0 = s1; s1 = s2; s2 = s3; s3 = 0;
      if (s0 == 0){
        unsigned long long best = 0;
        #pragma unroll
        for (int m = 0; m < 32; m++){
          int j = m * 64 + lane;
          unsigned long long pk = ((unsigned long long)ordf(nd[m]) << 32) | (unsigned)(2047 - j);
          if (pk < lastPop && pk > best) best = pk;
        }
        s0 = best;
      }
    }
  }
}

// ------------- graph-feature layer: stats pass (p-norm sums per channel, 21 ch) --------
__global__ __launch_bounds__(256) void gf_stats(const float* __restrict__ x, const int* __restrict__ idx,
                                                const float* __restrict__ Wf, double* __restrict__ sums){
  int tid0 = blockIdx.x * 256 + threadIdx.x;
  float s[21], q[21];
  #pragma unroll
  for (int o = 0; o < 21; o++){ s[o] = 0.f; q[o] = 0.f; }
  for (int pix = tid0; pix < BATCH * NP * KNN; pix += 256 * 256){
    int rem = pix / KNN;
    int n = rem & 2047, b = rem >> 11;
    int j = idx[pix];
    const float* xb = x + b * 3 * NP;
    float c0 = xb[n], c1 = xb[NP + n], c2 = xb[2*NP + n];
    float a0 = xb[j], a1 = xb[NP + j], a2 = xb[2*NP + j];
    float r0 = a0 - c0, r1 = a1 - c1, r2 = a2 - c2;
    float g0 = a1*c2 - a2*c1, g1 = a2*c0 - a0*c2, g2 = a0*c1 - a1*c0;
    #pragma unroll
    for (int o = 0; o < 21; o++){
      float w0 = Wf[o*3], w1 = Wf[o*3+1], w2 = Wf[o*3+2];
      float p0 = w0*r0 + w1*c0 + w2*g0;
      float p1 = w0*r1 + w1*c1 + w2*g1;
      float p2 = w0*r2 + w1*c2 + w2*g2;
      float nm = sqrtf(p0*p0 + p1*p1 + p2*p2) + EPSF;
      s[o] += nm; q[o] += nm * nm;
    }
  }
  __shared__ float bs[4][42];
  int w = threadIdx.x >> 6;
  #pragma unroll
  for (int o = 0; o < 21; o++){
    float a = s[o], bb = q[o];
    #pragma unroll
    for (int st = 1; st < 64; st <<= 1){ a += __shfl_xor(a, st, 64); bb += __shfl_xor(bb, st, 64); }
    if ((threadIdx.x & 63) == 0){ bs[w][o] = a; bs[w][21 + o] = bb; }
  }
  __syncthreads();
  if (threadIdx.x < 42){
    float tot = bs[0][threadIdx.x] + bs[1][threadIdx.x] + bs[2][threadIdx.x] + bs[3][threadIdx.x];
    int o = threadIdx.x % 21, sq = threadIdx.x / 21;
    atomicAdd(&sums[2*o + sq], (double)tot);
  }
}

// -------- graph-feature layer: apply bn+lrelu, then max-pool over K (fused) ------------
__global__ __launch_bounds__(256) void gf_applypool(const float* __restrict__ x, const int* __restrict__ idx,
    const float* __restrict__ Wf, const float* __restrict__ Wd, const float* __restrict__ Wg,
    const float* __restrict__ mi, float* __restrict__ h1){
  int w = threadIdx.x >> 6, lane = threadIdx.x & 63;
  int pix = blockIdx.x * 4 + w;
  int n = pix & 2047, b = pix >> 11;
  const float* xb = x + b * 3 * NP;
  float c0 = xb[n], c1 = xb[NP + n], c2 = xb[2*NP + n];
  int j = (lane < KNN) ? idx[pix * KNN + lane] : n;
  float a0 = xb[j], a1 = xb[NP + j], a2 = xb[2*NP + j];
  float r0 = a0 - c0, r1 = a1 - c1, r2 = a2 - c2;
  float g0 = a1*c2 - a2*c1, g1 = a2*c0 - a0*c2, g2 = a0*c1 - a1*c0;
  float h[21][3];
  #pragma unroll
  for (int o = 0; o < 21; o++){
    float w0 = Wf[o*3], w1 = Wf[o*3+1], w2 = Wf[o*3+2];
    float p0 = w0*r0 + w1*c0 + w2*g0;
    float p1 = w0*r1 + w1*c1 + w2*g1;
    float p2 = w0*r2 + w1*c2 + w2*g2;
    float nm = sqrtf(p0*p0 + p1*p1 + p2*p2) + EPSF;
    float f = (nm - mi[2*o]) * mi[2*o+1] / nm;
    p0 *= f; p1 *= f; p2 *= f;
    float v0 = Wd[o*3], v1 = Wd[o*3+1], v2 = Wd[o*3+2];
    float d0 = v0*r0 + v1*c0 + v2*g0;
    float d1 = v0*r1 + v1*c1 + v2*g1;
    float d2 = v0*r2 + v1*c2 + v2*g2;
    float dot = p0*d0 + p1*d1 + p2*d2;
    float dsq = d0*d0 + d1*d1 + d2*d2;
    float t = dot / (dsq + EPSF);
    h[o][0] = (dot >= 0.f) ? p0 : fmaf(-t, d0, p0);
    h[o][1] = (dot >= 0.f) ? p1 : fmaf(-t, d1, p1);
    h[o][2] = (dot >= 0.f) ? p2 : fmaf(-t, d2, p2);
  }
  #pragma unroll
  for (int o = 0; o < 21; o++){
    float q0 = 0.f, q1 = 0.f, q2 = 0.f;
    #pragma unroll
    for (int c = 0; c < 21; c++){
      float wg = Wg[o*21 + c];
      q0 = fmaf(wg, h[c][0], q0); q1 = fmaf(wg, h[c][1], q1); q2 = fmaf(wg, h[c][2], q2);
    }
    float dp = q0*h[o][0] + q1*h[o][1] + q2*h[o][2];
    float m = (lane < KNN) ? dp : -INFINITY;
    #pragma unroll
    for (int s = 32; s > 0; s >>= 1) m = fmaxf(m, __shfl_xor(m, s, 64));
    unsigned long long msk = __ballot(lane < KNN && dp == m);
    int wl = __ffsll(msk) - 1;
    float o0 = __shfl(h[o][0], wl, 64);
    float o1 = __shfl(h[o][1], wl, 64);
    float o2 = __shfl(h[o][2], wl, 64);
    if (lane == 0){
      float* dst = h1 + (size_t)((b*21 + o)*3) * NP + n;
      dst[0] = o0; dst[NP] = o1; dst[2*NP] = o2;
    }
  }
}

// ---------------- generic VN layer: stats + apply (thread per (b,n)) ------------------
template<int CIN>
__global__ __launch_bounds__(256) void layer_stats(const float* __restrict__ hin, const float* __restrict__ Wf,
                                                   double* __restrict__ sums, int Co, int oPerG){
  int tid = blockIdx.x * 256 + threadIdx.x;
  int n = tid & 2047, b = tid >> 11;
  int o0 = blockIdx.y * oPerG;
  int o1 = o0 + oPerG; if (o1 > Co) o1 = Co;
  float h[CIN*3];
  #pragma unroll
  for (int c = 0; c < CIN; c++){
    #pragma unroll
    for (int e = 0; e < 3; e++) h[c*3+e] = hin[(size_t)((b*CIN + c)*3 + e) * NP + n];
  }
  int lane = threadIdx.x & 63;
  for (int o = o0; o < o1; o++){
    float p0 = 0.f, p1 = 0.f, p2 = 0.f;
    #pragma unroll
    for (int c = 0; c < CIN; c++){
      float wv = Wf[o*CIN + c];
      p0 = fmaf(wv, h[c*3], p0); p1 = fmaf(wv, h[c*3+1], p1); p2 = fmaf(wv, h[c*3+2], p2);
    }
    float nm = sqrtf(p0*p0 + p1*p1 + p2*p2) + EPSF;
    float v1 = nm, v2 = nm * nm;
    #pragma unroll
    for (int st = 1; st < 64; st <<= 1){ v1 += __shfl_xor(v1, st, 64); v2 += __shfl_xor(v2, st, 64); }
    if (lane == 0){ atomicAdd(&sums[2*o], (double)v1); atomicAdd(&sums[2*o+1], (double)v2); }
  }
}

template<int CIN>
__global__ __launch_bounds__(256) void layer_apply(const float* __restrict__ hin, const float* __restrict__ Wf,
    const float* __restrict__ Wd, const float* __restrict__ mi, float* __restrict__ hout, int Co, int oPerG){
  int tid = blockIdx.x * 256 + threadIdx.x;
  int n = tid & 2047, b = tid >> 11;
  int o0 = blockIdx.y * oPerG;
  int o1 = o0 + oPerG; if (o1 > Co) o1 = Co;
  float h[CIN*3];
  #pragma unroll
  for (int c = 0; c < CIN; c++){
    #pragma unroll
    for (int e = 0; e < 3; e++) h[c*3+e] = hin[(size_t)((b*CIN + c)*3 + e) * NP + n];
  }
  for (int o = o0; o < o1; o++){
    float p0 = 0.f, p1 = 0.f, p2 = 0.f, d0 = 0.f, d1 = 0.f, d2 = 0.f;
    #pragma unroll
    for (int c = 0; c < CIN; c++){
      float wv = Wf[o*CIN + c], vv = Wd[o*CIN + c];
      p0 = fmaf(wv, h[c*3], p0); p1 = fmaf(wv, h[c*3+1], p1); p2 = fmaf(wv, h[c*3+2], p2);
      d0 = fmaf(vv, h[c*3], d0); d1 = fmaf(vv, h[c*3+1], d1); d2 = fmaf(vv, h[c*3+2], d2);
    }
    float nm = sqrtf(p0*p0 + p1*p1 + p2*p2) + EPSF;
    float f = (nm - mi[2*o]) * mi[2*o+1] / nm;
    p0 *= f; p1 *= f; p2 *= f;
    float dot = p0*d0 + p1*d1 + p2*d2;
    float dsq = d0*d0 + d1*d1 + d2*d2;
    float t = dot / (dsq + EPSF);
    float r0 = (dot >= 0.f) ? p0 : fmaf(-t, d0, p0);
    float r1 = (dot >= 0.f) ? p1 : fmaf(-t, d1, p1);
    float r2 = (dot >= 0.f) ? p2 : fmaf(-t, d2, p2);
    float* dst = hout + (size_t)((b*Co + o)*3) * NP + n;
    dst[0] = r0; dst[NP] = r1; dst[2*NP] = r2;
  }
}

__global__ void finalize_stats(const double* __restrict__ sums, float* __restrict__ mi, int Co, double invM){
  int o = blockIdx.x * 64 + threadIdx.x;
  if (o >= Co) return;
  double m = sums[2*o] * invM;
  double v = sums[2*o+1] * invM - m * m;
  if (v < 0.0) v = 0.0;
  mi[2*o] = (float)m;
  mi[2*o+1] = (float)(1.0 / sqrt(v + (double)BNEPS));
}

// ----------------- transpose+pad W_pool: Wt[c][o], 352 x 384, zero-padded --------------
__global__ __launch_bounds__(256) void wt_kernel(const float* __restrict__ Wp, float* __restrict__ Wt){
  int t = blockIdx.x * 256 + threadIdx.x;
  if (t >= 352 * 384) return;
  int c = t / 384, o = t % 384;
  Wt[t] = (c < 341 && o < 341) ? Wp[o*341 + c] : 0.f;
}

// ------------- pool over N: D = W_pool @ H per (b,e); dot; packed argmax ---------------
// 128x128 tile, 8x8 microtile, k-major LDS, conflict-free reads (split-half n mapping)
__global__ __launch_bounds__(256) void pool_gemm2(const float* __restrict__ h4, const float* __restrict__ Wt,
                                                  unsigned long long* __restrict__ packed){
  __shared__ float sW[32][128];
  __shared__ float sH[32][128];
  const int b = blockIdx.z, o0 = blockIdx.y * 128, n0 = blockIdx.x * 128;
  const int t = threadIdx.x, tx = t & 15, ty = t >> 4;
  const int scol = (t & 31) * 4, srow = t >> 5;
  float dot[8][8];
  #pragma unroll
  for (int r = 0; r < 8; r++)
    #pragma unroll
    for (int q = 0; q < 8; q++) dot[r][q] = 0.f;
  for (int e = 0; e < 3; e++){
    float acc[8][8];
    #pragma unroll
    for (int r = 0; r < 8; r++)
      #pragma unroll
      for (int q = 0; q < 8; q++) acc[r][q] = 0.f;
    for (int c0 = 0; c0 < 352; c0 += 32){
      #pragma unroll
      for (int it = 0; it < 4; it++){
        int kk = it * 8 + srow;
        int c = c0 + kk;
        *(float4*)&sW[kk][scol] = *(const float4*)&Wt[(size_t)c * 384 + o0 + scol];
        float4 hv = make_float4(0.f, 0.f, 0.f, 0.f);
        if (c < 341) hv = *(const float4*)&h4[((size_t)((b*341 + c)*3 + e) << 11) + n0 + scol];
        *(float4*)&sH[kk][scol] = hv;
      }
      __syncthreads();
      #pragma unroll
      for (int kk = 0; kk < 32; kk++){
        float4 w0 = *(const float4*)&sW[kk][ty*8];
        float4 w1 = *(const float4*)&sW[kk][ty*8 + 4];
        float4 h0 = *(const float4*)&sH[kk][tx*4];
        float4 h1 = *(const float4*)&sH[kk][64 + tx*4];
        float wa[8] = {w0.x, w0.y, w0.z, w0.w, w1.x, w1.y, w1.z, w1.w};
        float ha[8] = {h0.x, h0.y, h0.z, h0.w, h1.x, h1.y, h1.z, h1.w};
        #pragma unroll
        for (int r = 0; r < 8; r++)
          #pragma unroll
          for (int q = 0; q < 8; q++) acc[r][q] = fmaf(wa[r], ha[q], acc[r][q]);
      }
      __syncthreads();
    }
    #pragma unroll
    for (int r = 0; r < 8; r++){
      int o = o0 + ty*8 + r;
      if (o < 341){
        const float* hp = &h4[((size_t)((b*341 + o)*3 + e) << 11) + n0];
        float4 p0 = *(const float4*)&hp[tx*4];
        float4 p1 = *(const float4*)&hp[64 + tx*4];
        dot[r][0] = fmaf(acc[r][0], p0.x, dot[r][0]);
        dot[r][1] = fmaf(acc[r][1], p0.y, dot[r][1]);
        dot[r][2] = fmaf(acc[r][2], p0.z, dot[r][2]);
        dot[r][3] = fmaf(acc[r][3], p0.w, dot[r][3]);
        dot[r][4] = fmaf(acc[r][4], p1.x, dot[r][4]);
        dot[r][5] = fmaf(acc[r][5], p1.y, dot[r][5]);
        dot[r][6] = fmaf(acc[r][6], p1.z, dot[r][6]);
        dot[r][7] = fmaf(acc[r][7], p1.w, dot[r][7]);
      }
    }
  }
  #pragma unroll
  for (int r = 0; r < 8; r++){
    unsigned long long best = 0;
    #pragma unroll
    for (int q = 0; q < 8; q++){
      int nn = n0 + (q < 4 ? tx*4 + q : 64 + tx*4 + (q - 4));
      unsigned long long pk = ((unsigned long long)ordf(dot[r][q]) << 32) | (unsigned)(2047 - nn);
      if (pk > best) best = pk;
    }
    #pragma unroll
    for (int s = 1; s < 16; s <<= 1){
      unsigned long long ob = __shfl_xor(best, s, 64);
      if (ob > best) best = ob;
    }
    int o = o0 + ty*8 + r;
    if (tx == 0 && o < 341) atomicMax(&packed[b*341 + o], best);
  }
}

__global__ void pool_gather(const unsigned long long* __restrict__ packed, const float* __restrict__ h4,
                            float* __restrict__ pooled){
  int t = blockIdx.x * 256 + threadIdx.x;
  if (t >= BATCH * 341) return;
  int n = 2047 - (int)(packed[t] & 0xffffffffu);
  pooled[t*3 + 0] = h4[(size_t)(t*3 + 0) * NP + n];
  pooled[t*3 + 1] = h4[(size_t)(t*3 + 1) * NP + n];
  pooled[t*3 + 2] = h4[(size_t)(t*3 + 2) * NP + n];
}

// -------- fully-connected VN layer (B=8 pixels, per-channel bn over B) -----------------
__global__ __launch_bounds__(64) void flayer(const float* __restrict__ in, const float* __restrict__ Wf,
    const float* __restrict__ Wd, float* __restrict__ out, int Cin, int Co){
  int o = blockIdx.x, lane = threadIdx.x;
  float pv[24], dv[24];
  #pragma unroll
  for (int be = 0; be < 24; be++){ pv[be] = 0.f; dv[be] = 0.f; }
  for (int c = lane; c < Cin; c += 64){
    float wf = Wf[o*Cin + c], wd = Wd[o*Cin + c];
    #pragma unroll
    for (int bb = 0; bb < 8; bb++){
      #pragma unroll
      for (int e = 0; e < 3; e++){
        float hv = in[(bb*Cin + c)*3 + e];
        pv[bb*3+e] = fmaf(wf, hv, pv[bb*3+e]);
        dv[bb*3+e] = fmaf(wd, hv, dv[bb*3+e]);
      }
    }
  }
  #pragma unroll
  for (int be = 0; be < 24; be++){
    #pragma unroll
    for (int st = 1; st < 64; st <<= 1){
      pv[be] += __shfl_xor(pv[be], st, 64);
      dv[be] += __shfl_xor(dv[be], st, 64);
    }
  }
  float nm[8], dotb[8], dsqb[8];
  float mean = 0.f;
  #pragma unroll
  for (int bb = 0; bb < 8; bb++){
    nm[bb] = sqrtf(pv[bb*3]*pv[bb*3] + pv[bb*3+1]*pv[bb*3+1] + pv[bb*3+2]*pv[bb*3+2]) + EPSF;
    mean += nm[bb];
  }
  mean *= 0.125f;
  float var = 0.f;
  #pragma unroll
  for (int bb = 0; bb < 8; bb++){ float dvv = nm[bb] - mean; var += dvv * dvv; }
  var *= 0.125f;
  float istd = 1.f / sqrtf(var + BNEPS);
  #pragma unroll
  for (int bb = 0; bb < 8; bb++){
    float f = (nm[bb] - mean) * istd / nm[bb];
    dotb[bb] = f * (pv[bb*3]*dv[bb*3] + pv[bb*3+1]*dv[bb*3+1] + pv[bb*3+2]*dv[bb*3+2]);
    dsqb[bb] = dv[bb*3]*dv[bb*3] + dv[bb*3+1]*dv[bb*3+1] + dv[bb*3+2]*dv[bb*3+2];
  }
  #pragma unroll
  for (int be = 0; be < 24; be++){
    if (lane == be){
      int bb = be / 3;
      float f = (nm[bb] - mean) * istd / nm[bb];
      float pe = pv[be] * f;
      float t = dotb[bb] / (dsqb[bb] + EPSF);
      float res = (dotb[bb] >= 0.f) ? pe : fmaf(-t, dv[be], pe);
      out[(bb*Co + o)*3 + (be % 3)] = res;
    }
  }
}

__global__ void final_lin(const float* __restrict__ in, const float* __restrict__ W, float* __restrict__ out){
  int t = threadIdx.x;
  if (t >= 72) return;
  int b = t / 9, o = (t % 9) / 3, e = t % 3;
  float s = 0.f;
  for (int c = 0; c < 85; c++) s = fmaf(W[o*85 + c], in[(b*85 + c)*3 + e], s);
  out[t] = s;
}

// --------------------------------- launcher -------------------------------------------
extern "C" void kernel_launch(void* const* d_in, const int* in_sizes, int n_in,
                              void* d_out, int out_size, void* d_ws, size_t ws_size,
                              hipStream_t stream){
  const float* x   = (const float*)d_in[0];
  const float* Wpf = (const float*)d_in[1];
  const float* Wpd = (const float*)d_in[2];
  const float* Wg  = (const float*)d_in[3];
  const float* W1f = (const float*)d_in[4];
  const float* W1d = (const float*)d_in[5];
  const float* W2f = (const float*)d_in[6];
  const float* W2d = (const float*)d_in[7];
  const float* W3f = (const float*)d_in[8];
  const float* W3d = (const float*)d_in[9];
  const float* Wpool = (const float*)d_in[10];
  const float* Wf1f = (const float*)d_in[11];
  const float* Wf1d = (const float*)d_in[12];
  const float* Wf2f = (const float*)d_in[13];
  const float* Wf2d = (const float*)d_in[14];
  const float* Wf3  = (const float*)d_in[15];
  float* out = (float*)d_out;

  char* ws = (char*)d_ws;
  size_t off = 0;
  int*   idx = (int*)(ws + off);              off += (size_t)BATCH*NP*KNN*4;
  float* h1  = (float*)(ws + off);            off += (size_t)BATCH*21*3*NP*4;
  float* h2  = (float*)(ws + off);            off += (size_t)BATCH*21*3*NP*4;
  float* h3  = (float*)(ws + off);            off += (size_t)BATCH*42*3*NP*4;
  float* h4  = (float*)(ws + off);            off += (size_t)BATCH*341*3*NP*4;
  float* Wt  = (float*)(ws + off);            off += (size_t)352*384*4;
  char*  zbase = ws + off;
  double* sums_gf = (double*)(ws + off);      off += 8192;
  double* sums_l1 = (double*)(ws + off);      off += 8192;
  double* sums_l2 = (double*)(ws + off);      off += 8192;
  double* sums_l3 = (double*)(ws + off);      off += 8192;
  unsigned long long* packed = (unsigned long long*)(ws + off); off += 24576;
  size_t zbytes = (ws + off) - zbase;
  float* mi_gf = (float*)(ws + off);          off += 1024;
  float* mi_l1 = (float*)(ws + off);          off += 1024;
  float* mi_l2 = (float*)(ws + off);          off += 1024;
  float* mi_l3 = (float*)(ws + off);          off += 4096;
  float* pooled = (float*)(ws + off);         off += (size_t)BATCH*341*3*4 + 32;
  float* h5 = (float*)(ws + off);             off += (size_t)BATCH*170*3*4 + 32;
  float* h6 = (float*)(ws + off);             off += (size_t)BATCH*85*3*4 + 32;

  hipMemsetAsync(zbase, 0, zbytes, stream);

  knn_kernel<<<BATCH*NP/4, 256, 0, stream>>>(x, idx);
  wt_kernel<<<(352*384 + 255)/256, 256, 0, stream>>>(Wpool, Wt);

  gf_stats<<<256, 256, 0, stream>>>(x, idx, Wpf, sums_gf);
  finalize_stats<<<1, 64, 0, stream>>>(sums_gf, mi_gf, 21, 1.0 / (double)(BATCH*NP*KNN));
  gf_applypool<<<BATCH*NP/4, 256, 0, stream>>>(x, idx, Wpf, Wpd, Wg, mi_gf, h1);

  layer_stats<21><<<dim3(64,3), 256, 0, stream>>>(h1, W1f, sums_l1, 21, 7);
  finalize_stats<<<1, 64, 0, stream>>>(sums_l1, mi_l1, 21, 1.0 / (double)(BATCH*NP));
  layer_apply<21><<<dim3(64,3), 256, 0, stream>>>(h1, W1f, W1d, mi_l1, h2, 21, 7);

  layer_stats<21><<<dim3(64,3), 256, 0, stream>>>(h2, W2f, sums_l2, 42, 14);
  finalize_stats<<<1, 64, 0, stream>>>(sums_l2, mi_l2, 42, 1.0 / (double)(BATCH*NP));
  layer_apply<21><<<dim3(64,3), 256, 0, stream>>>(h2, W2f, W2d, mi_l2, h3, 42, 14);

  layer_stats<42><<<dim3(64,8), 256, 0, stream>>>(h3, W3f, sums_l3, 341, 43);
  finalize_stats<<<6, 64, 0, stream>>>(sums_l3, mi_l3, 341, 1.0 / (double)(BATCH*NP));
  layer_apply<42><<<dim3(64,8), 256, 0, stream>>>(h3, W3f, W3d, mi_l3, h4, 341, 43);

  pool_gemm2<<<dim3(16, 3, BATCH), 256, 0, stream>>>(h4, Wt, packed);
  pool_gather<<<(BATCH*341 + 255)/256, 256, 0, stream>>>(packed, h4, pooled);

  flayer<<<170, 64, 0, stream>>>(pooled, Wf1f, Wf1d, h5, 341, 170);
  flayer<<<85, 64, 0, stream>>>(h5, Wf2f, Wf2d, h6, 170, 85);
  final_lin<<<1, 128, 0, stream>>>(h6, Wf3, out);
}

// Round 3
// 822.462 us; speedup vs baseline: 1.4458x; 1.3066x over previous
//
#include <hip/hip_runtime.h>

#define NP 2048
#define BATCH 8
#define KNN 40
#define EPSF 1e-6f
#define BNEPS 1e-5f

typedef __attribute__((ext_vector_type(8))) short short8;
typedef __attribute__((ext_vector_type(4))) float f32x4;

__device__ __forceinline__ unsigned ordf(float v){
  unsigned u = __float_as_uint(v);
  return (u & 0x80000000u) ? ~u : (u | 0x80000000u);
}

__device__ __forceinline__ unsigned long long wmax64(unsigned long long v){
  #pragma unroll
  for (int s = 32; s > 0; s >>= 1){
    unsigned long long o = __shfl_xor(v, s, 64);
    v = (o > v) ? o : v;
  }
  return v;
}

// split fp32 -> bf16 hi (RNE) + bf16 lo (RNE of residual)
__device__ __forceinline__ void bsplit(float v, unsigned short &h, unsigned short &l){
  unsigned u = __float_as_uint(v);
  unsigned hu = (u + 0x7fffu + ((u >> 16) & 1u)) >> 16;
  h = (unsigned short)hu;
  float r = v - __uint_as_float(hu << 16);
  unsigned u2 = __float_as_uint(r);
  l = (unsigned short)((u2 + 0x7fffu + ((u2 >> 16) & 1u)) >> 16);
}

__device__ __forceinline__ float bf2f(unsigned short h){
  return __uint_as_float(((unsigned)h) << 16);
}

// ---------------- KNN: exact top-40 (nearest incl. self), tie -> lowest index ----------
__global__ __launch_bounds__(256) void knn_kernel(const float* __restrict__ x, int* __restrict__ idx){
  __shared__ float sx0[NP], sx1[NP], sx2[NP], sxx[NP];
  int tid = threadIdx.x;
  int w = tid >> 6, lane = tid & 63;
  int row = blockIdx.x * 4 + w;
  int b = row >> 11, i = row & 2047;
  const float* xb = x + b * 3 * NP;
  for (int t = tid; t < NP; t += 256){ sx0[t] = xb[t]; sx1[t] = xb[NP + t]; sx2[t] = xb[2*NP + t]; }
  __syncthreads();
  for (int t = tid; t < NP; t += 256){
    float a = sx0[t], c = sx1[t], d = sx2[t];
    sxx[t] = __fadd_rn(__fadd_rn(__fmul_rn(a,a), __fmul_rn(c,c)), __fmul_rn(d,d));
  }
  __syncthreads();
  float xi0 = sx0[i], xi1 = sx1[i], xi2 = sx2[i], xxi = sxx[i];
  float nd[32];
  unsigned long long s0 = 0, s1 = 0, s2 = 0, s3 = 0;
  #pragma unroll
  for (int m = 0; m < 32; m++){
    int j = m * 64 + lane;
    float dot = __fadd_rn(__fadd_rn(__fmul_rn(xi0, sx0[j]), __fmul_rn(xi1, sx1[j])), __fmul_rn(xi2, sx2[j]));
    float v = __fsub_rn(__fsub_rn(-xxi, __fmul_rn(-2.f, dot)), sxx[j]);
    nd[m] = v;
    unsigned long long pk = ((unsigned long long)ordf(v) << 32) | (unsigned)(2047 - j);
    if (pk > s3){
      if (pk > s2){ s3 = s2; if (pk > s1){ s2 = s1; if (pk > s0){ s1 = s0; s0 = pk; } else s1 = pk; } else s2 = pk; }
      else s3 = pk;
    }
  }
  unsigned long long lastPop = ~0ull;
  int* outp = idx + row * KNN;
  for (int kk = 0; kk < KNN; kk++){
    unsigned long long g = wmax64(s0);
    if (s0 == g){
      outp[kk] = 2047 - (int)(g & 0xffffffffu);
      lastPop = g;
      s0 = s1; s1 = s2; s2 = s3; s3 = 0;
      if (s0 == 0){
        unsigned long long best = 0;
        #pragma unroll
        for (int m = 0; m < 32; m++){
          int j = m * 64 + lane;
          unsigned long long pk = ((unsigned long long)ordf(nd[m]) << 32) | (unsigned)(2047 - j);
          if (pk < lastPop && pk > best) best = pk;
        }
        s0 = best;
      }
    }
  }
}

// ------------- graph-feature layer: stats pass (p-norm sums per channel, 21 ch) --------
__global__ __launch_bounds__(256) void gf_stats(const float* __restrict__ x, const int* __restrict__ idx,
                                                const float* __restrict__ Wf, double* __restrict__ sums){
  int tid0 = blockIdx.x * 256 + threadIdx.x;
  float s[21], q[21];
  #pragma unroll
  for (int o = 0; o < 21; o++){ s[o] = 0.f; q[o] = 0.f; }
  for (int pix = tid0; pix < BATCH * NP * KNN; pix += 256 * 256){
    int rem = pix / KNN;
    int n = rem & 2047, b = rem >> 11;
    int j = idx[pix];
    const float* xb = x + b * 3 * NP;
    float c0 = xb[n], c1 = xb[NP + n], c2 = xb[2*NP + n];
    float a0 = xb[j], a1 = xb[NP + j], a2 = xb[2*NP + j];
    float r0 = a0 - c0, r1 = a1 - c1, r2 = a2 - c2;
    float g0 = a1*c2 - a2*c1, g1 = a2*c0 - a0*c2, g2 = a0*c1 - a1*c0;
    #pragma unroll
    for (int o = 0; o < 21; o++){
      float w0 = Wf[o*3], w1 = Wf[o*3+1], w2 = Wf[o*3+2];
      float p0 = w0*r0 + w1*c0 + w2*g0;
      float p1 = w0*r1 + w1*c1 + w2*g1;
      float p2 = w0*r2 + w1*c2 + w2*g2;
      float nm = sqrtf(p0*p0 + p1*p1 + p2*p2) + EPSF;
      s[o] += nm; q[o] += nm * nm;
    }
  }
  __shared__ float bs[4][42];
  int w = threadIdx.x >> 6;
  #pragma unroll
  for (int o = 0; o < 21; o++){
    float a = s[o], bb = q[o];
    #pragma unroll
    for (int st = 1; st < 64; st <<= 1){ a += __shfl_xor(a, st, 64); bb += __shfl_xor(bb, st, 64); }
    if ((threadIdx.x & 63) == 0){ bs[w][o] = a; bs[w][21 + o] = bb; }
  }
  __syncthreads();
  if (threadIdx.x < 42){
    float tot = bs[0][threadIdx.x] + bs[1][threadIdx.x] + bs[2][threadIdx.x] + bs[3][threadIdx.x];
    int o = threadIdx.x % 21, sq = threadIdx.x / 21;
    atomicAdd(&sums[2*o + sq], (double)tot);
  }
}

// -------- graph-feature layer: apply bn+lrelu, then max-pool over K (fused) ------------
__global__ __launch_bounds__(256) void gf_applypool(const float* __restrict__ x, const int* __restrict__ idx,
    const float* __restrict__ Wf, const float* __restrict__ Wd, const float* __restrict__ Wg,
    const float* __restrict__ mi, float* __restrict__ h1){
  int w = threadIdx.x >> 6, lane = threadIdx.x & 63;
  int pix = blockIdx.x * 4 + w;
  int n = pix & 2047, b = pix >> 11;
  const float* xb = x + b * 3 * NP;
  float c0 = xb[n], c1 = xb[NP + n], c2 = xb[2*NP + n];
  int j = (lane < KNN) ? idx[pix * KNN + lane] : n;
  float a0 = xb[j], a1 = xb[NP + j], a2 = xb[2*NP + j];
  float r0 = a0 - c0, r1 = a1 - c1, r2 = a2 - c2;
  float g0 = a1*c2 - a2*c1, g1 = a2*c0 - a0*c2, g2 = a0*c1 - a1*c0;
  float h[21][3];
  #pragma unroll
  for (int o = 0; o < 21; o++){
    float w0 = Wf[o*3], w1 = Wf[o*3+1], w2 = Wf[o*3+2];
    float p0 = w0*r0 + w1*c0 + w2*g0;
    float p1 = w0*r1 + w1*c1 + w2*g1;
    float p2 = w0*r2 + w1*c2 + w2*g2;
    float nm = sqrtf(p0*p0 + p1*p1 + p2*p2) + EPSF;
    float f = (nm - mi[2*o]) * mi[2*o+1] / nm;
    p0 *= f; p1 *= f; p2 *= f;
    float v0 = Wd[o*3], v1 = Wd[o*3+1], v2 = Wd[o*3+2];
    float d0 = v0*r0 + v1*c0 + v2*g0;
    float d1 = v0*r1 + v1*c1 + v2*g1;
    float d2 = v0*r2 + v1*c2 + v2*g2;
    float dot = p0*d0 + p1*d1 + p2*d2;
    float dsq = d0*d0 + d1*d1 + d2*d2;
    float t = dot / (dsq + EPSF);
    h[o][0] = (dot >= 0.f) ? p0 : fmaf(-t, d0, p0);
    h[o][1] = (dot >= 0.f) ? p1 : fmaf(-t, d1, p1);
    h[o][2] = (dot >= 0.f) ? p2 : fmaf(-t, d2, p2);
  }
  #pragma unroll
  for (int o = 0; o < 21; o++){
    float q0 = 0.f, q1 = 0.f, q2 = 0.f;
    #pragma unroll
    for (int c = 0; c < 21; c++){
      float wg = Wg[o*21 + c];
      q0 = fmaf(wg, h[c][0], q0); q1 = fmaf(wg, h[c][1], q1); q2 = fmaf(wg, h[c][2], q2);
    }
    float dp = q0*h[o][0] + q1*h[o][1] + q2*h[o][2];
    float m = (lane < KNN) ? dp : -INFINITY;
    #pragma unroll
    for (int s = 32; s > 0; s >>= 1) m = fmaxf(m, __shfl_xor(m, s, 64));
    unsigned long long msk = __ballot(lane < KNN && dp == m);
    int wl = __ffsll(msk) - 1;
    float o0 = __shfl(h[o][0], wl, 64);
    float o1 = __shfl(h[o][1], wl, 64);
    float o2 = __shfl(h[o][2], wl, 64);
    if (lane == 0){
      float* dst = h1 + (size_t)((b*21 + o)*3) * NP + n;
      dst[0] = o0; dst[NP] = o1; dst[2*NP] = o2;
    }
  }
}

// ---------------- generic VN layer: stats + apply (thread per (b,n)) ------------------
template<int CIN>
__global__ __launch_bounds__(256) void layer_stats(const float* __restrict__ hin, const float* __restrict__ Wf,
                                                   double* __restrict__ sums, int Co, int oPerG){
  int tid = blockIdx.x * 256 + threadIdx.x;
  int n = tid & 2047, b = tid >> 11;
  int o0 = blockIdx.y * oPerG;
  int o1 = o0 + oPerG; if (o1 > Co) o1 = Co;
  float h[CIN*3];
  #pragma unroll
  for (int c = 0; c < CIN; c++){
    #pragma unroll
    for (int e = 0; e < 3; e++) h[c*3+e] = hin[(size_t)((b*CIN + c)*3 + e) * NP + n];
  }
  int lane = threadIdx.x & 63;
  for (int o = o0; o < o1; o++){
    float p0 = 0.f, p1 = 0.f, p2 = 0.f;
    #pragma unroll
    for (int c = 0; c < CIN; c++){
      float wv = Wf[o*CIN + c];
      p0 = fmaf(wv, h[c*3], p0); p1 = fmaf(wv, h[c*3+1], p1); p2 = fmaf(wv, h[c*3+2], p2);
    }
    float nm = sqrtf(p0*p0 + p1*p1 + p2*p2) + EPSF;
    float v1 = nm, v2 = nm * nm;
    #pragma unroll
    for (int st = 1; st < 64; st <<= 1){ v1 += __shfl_xor(v1, st, 64); v2 += __shfl_xor(v2, st, 64); }
    if (lane == 0){ atomicAdd(&sums[2*o], (double)v1); atomicAdd(&sums[2*o+1], (double)v2); }
  }
}

template<int CIN>
__global__ __launch_bounds__(256) void layer_apply(const float* __restrict__ hin, const float* __restrict__ Wf,
    const float* __restrict__ Wd, const float* __restrict__ mi, float* __restrict__ hout, int Co, int oPerG){
  int tid = blockIdx.x * 256 + threadIdx.x;
  int n = tid & 2047, b = tid >> 11;
  int o0 = blockIdx.y * oPerG;
  int o1 = o0 + oPerG; if (o1 > Co) o1 = Co;
  float h[CIN*3];
  #pragma unroll
  for (int c = 0; c < CIN; c++){
    #pragma unroll
    for (int e = 0; e < 3; e++) h[c*3+e] = hin[(size_t)((b*CIN + c)*3 + e) * NP + n];
  }
  for (int o = o0; o < o1; o++){
    float p0 = 0.f, p1 = 0.f, p2 = 0.f, d0 = 0.f, d1 = 0.f, d2 = 0.f;
    #pragma unroll
    for (int c = 0; c < CIN; c++){
      float wv = Wf[o*CIN + c], vv = Wd[o*CIN + c];
      p0 = fmaf(wv, h[c*3], p0); p1 = fmaf(wv, h[c*3+1], p1); p2 = fmaf(wv, h[c*3+2], p2);
      d0 = fmaf(vv, h[c*3], d0); d1 = fmaf(vv, h[c*3+1], d1); d2 = fmaf(vv, h[c*3+2], d2);
    }
    float nm = sqrtf(p0*p0 + p1*p1 + p2*p2) + EPSF;
    float f = (nm - mi[2*o]) * mi[2*o+1] / nm;
    p0 *= f; p1 *= f; p2 *= f;
    float dot = p0*d0 + p1*d1 + p2*d2;
    float dsq = d0*d0 + d1*d1 + d2*d2;
    float t = dot / (dsq + EPSF);
    float r0 = (dot >= 0.f) ? p0 : fmaf(-t, d0, p0);
    float r1 = (dot >= 0.f) ? p1 : fmaf(-t, d1, p1);
    float r2 = (dot >= 0.f) ? p2 : fmaf(-t, d2, p2);
    float* dst = hout + (size_t)((b*Co + o)*3) * NP + n;
    dst[0] = r0; dst[NP] = r1; dst[2*NP] = r2;
  }
}

// ------- last VN layer (42->341): apply + write k-packed bf16 hi/lo (for MFMA pool) ----
// Hk layout: [b][e][kb=0..47][n=0..2047][j=0..7]  (channel c = kb*8+j), 16B granules
__global__ __launch_bounds__(256) void layer_apply_l3(const float* __restrict__ hin, const float* __restrict__ Wf,
    const float* __restrict__ Wd, const float* __restrict__ mi,
    unsigned short* __restrict__ Hkh, unsigned short* __restrict__ Hkl){
  int tid = blockIdx.x * 256 + threadIdx.x;
  int n = tid & 2047, b = tid >> 11;
  int o0 = blockIdx.y * 48;
  float h[126];
  #pragma unroll
  for (int c = 0; c < 42; c++){
    #pragma unroll
    for (int e = 0; e < 3; e++) h[c*3+e] = hin[(size_t)((b*42 + c)*3 + e) * NP + n];
  }
  for (int gq = 0; gq < 6; gq++){
    unsigned ph[3][4], pl[3][4];
    #pragma unroll
    for (int j = 0; j < 8; j++){
      int o = o0 + gq*8 + j;
      float r0 = 0.f, r1 = 0.f, r2 = 0.f;
      if (o < 341){
        float p0=0.f,p1=0.f,p2=0.f,d0=0.f,d1=0.f,d2=0.f;
        #pragma unroll
        for (int c = 0; c < 42; c++){
          float wv = Wf[o*42 + c], vv = Wd[o*42 + c];
          p0 = fmaf(wv, h[c*3], p0); p1 = fmaf(wv, h[c*3+1], p1); p2 = fmaf(wv, h[c*3+2], p2);
          d0 = fmaf(vv, h[c*3], d0); d1 = fmaf(vv, h[c*3+1], d1); d2 = fmaf(vv, h[c*3+2], d2);
        }
        float nm = sqrtf(p0*p0 + p1*p1 + p2*p2) + EPSF;
        float f = (nm - mi[2*o]) * mi[2*o+1] / nm;
        p0 *= f; p1 *= f; p2 *= f;
        float dot = p0*d0 + p1*d1 + p2*d2;
        float dsq = d0*d0 + d1*d1 + d2*d2;
        float t = dot / (dsq + EPSF);
        r0 = (dot >= 0.f) ? p0 : fmaf(-t, d0, p0);
        r1 = (dot >= 0.f) ? p1 : fmaf(-t, d1, p1);
        r2 = (dot >= 0.f) ? p2 : fmaf(-t, d2, p2);
      }
      unsigned short hh, ll;
      bsplit(r0, hh, ll);
      if (!(j & 1)){ ph[0][j>>1] = hh; pl[0][j>>1] = ll; }
      else { ph[0][j>>1] |= ((unsigned)hh) << 16; pl[0][j>>1] |= ((unsigned)ll) << 16; }
      bsplit(r1, hh, ll);
      if (!(j & 1)){ ph[1][j>>1] = hh; pl[1][j>>1] = ll; }
      else { ph[1][j>>1] |= ((unsigned)hh) << 16; pl[1][j>>1] |= ((unsigned)ll) << 16; }
      bsplit(r2, hh, ll);
      if (!(j & 1)){ ph[2][j>>1] = hh; pl[2][j>>1] = ll; }
      else { ph[2][j>>1] |= ((unsigned)hh) << 16; pl[2][j>>1] |= ((unsigned)ll) << 16; }
    }
    #pragma unroll
    for (int e = 0; e < 3; e++){
      size_t base = ((((size_t)(b*3 + e))*48 + (o0 >> 3) + gq) * 2048 + n) * 8;
      *(uint4*)(Hkh + base) = make_uint4(ph[e][0], ph[e][1], ph[e][2], ph[e][3]);
      *(uint4*)(Hkl + base) = make_uint4(pl[e][0], pl[e][1], pl[e][2], pl[e][3]);
    }
  }
}

__global__ void finalize_stats(const double* __restrict__ sums, float* __restrict__ mi, int Co, double invM){
  int o = blockIdx.x * 64 + threadIdx.x;
  if (o >= Co) return;
  double m = sums[2*o] * invM;
  double v = sums[2*o+1] * invM - m * m;
  if (v < 0.0) v = 0.0;
  mi[2*o] = (float)m;
  mi[2*o+1] = (float)(1.0 / sqrt(v + (double)BNEPS));
}

// ------- split W_pool into k-packed bf16 hi/lo: Wk[cb=0..43][o=0..383][j=0..7] ---------
__global__ __launch_bounds__(256) void wk_kernel(const float* __restrict__ Wp,
    unsigned short* __restrict__ Wkh, unsigned short* __restrict__ Wkl){
  int t = blockIdx.x * 256 + threadIdx.x;
  if (t >= 44*384*8) return;
  int j = t & 7, o = (t >> 3) % 384, cb = t / (384*8);
  int c = cb*8 + j;
  float v = (c < 341 && o < 341) ? Wp[o*341 + c] : 0.f;
  unsigned short h, l;
  bsplit(v, h, l);
  Wkh[t] = h; Wkl[t] = l;
}

// ------------- pool over N via split-bf16 MFMA: D = Wpool @ H; dot; argmax -------------
// grid (16 n-tiles, 6 o-tiles, 8 b), 256 thr. Block tile 64(o) x 128(n).
// Wave (w>>1): o-half 32 rows; (w&1): n-half 64 cols. 16x16x32 bf16 MFMA, 3-term split.
__global__ __launch_bounds__(256) void pool_mfma(const unsigned short* __restrict__ Wkh,
    const unsigned short* __restrict__ Wkl, const unsigned short* __restrict__ Hkh,
    const unsigned short* __restrict__ Hkl, unsigned long long* __restrict__ packed){
  __shared__ unsigned short sB[2][2][4][128][8];   // [buf][hi/lo][kb][n][j] = 32 KB
  const int b = blockIdx.z, o0 = blockIdx.y * 64, n0 = blockIdx.x * 128;
  const int t = threadIdx.x, w = t >> 6, l = t & 63;
  const int wo = o0 + (w >> 1) * 32;       // wave o base
  const int wnl = (w & 1) * 64;            // wave n base (LDS-local)
  const int r = l & 15, g = l >> 4;
  const int skb = t >> 7, sn = t & 127;    // staging coords (pass 0: kb=skb, pass 1: kb=skb+2)

  f32x4 acc[2][4], dotv[2][4];
  #pragma unroll
  for (int s = 0; s < 2; s++)
    #pragma unroll
    for (int nt = 0; nt < 4; nt++){ dotv[s][nt] = (f32x4)0.f; }

  auto gsrc = [&](const unsigned short* base, int e, int kt, int p) -> const uint4* {
    int kb = skb + p*2;
    return (const uint4*)(base + ((((size_t)(b*3 + e))*48 + (size_t)(kt*4 + kb)) * 2048 + n0 + sn) * 8);
  };

  uint4 rg[2][2];
  rg[0][0] = *gsrc(Hkh, 0, 0, 0); rg[1][0] = *gsrc(Hkh, 0, 0, 1);
  rg[0][1] = *gsrc(Hkl, 0, 0, 0); rg[1][1] = *gsrc(Hkl, 0, 0, 1);

  for (int ek = 0; ek < 33; ek++){
    const int e = ek / 11, kt = ek - e*11, buf = ek & 1;
    // write staged regs into LDS
    *(uint4*)&sB[buf][0][skb  ][sn][0] = rg[0][0];
    *(uint4*)&sB[buf][0][skb+2][sn][0] = rg[1][0];
    *(uint4*)&sB[buf][1][skb  ][sn][0] = rg[0][1];
    *(uint4*)&sB[buf][1][skb+2][sn][0] = rg[1][1];
    __syncthreads();
    // prefetch next k-tile into regs (overlaps MFMA below)
    if (ek < 32){
      int e2 = (ek+1) / 11, kt2 = (ek+1) - e2*11;
      rg[0][0] = *gsrc(Hkh, e2, kt2, 0); rg[1][0] = *gsrc(Hkh, e2, kt2, 1);
      rg[0][1] = *gsrc(Hkl, e2, kt2, 0); rg[1][1] = *gsrc(Hkl, e2, kt2, 1);
    }
    if (kt == 0){
      #pragma unroll
      for (int s = 0; s < 2; s++)
        #pragma unroll
        for (int nt = 0; nt < 4; nt++) acc[s][nt] = (f32x4)0.f;
    }
    // A fragments straight from global (L2-hot, 270 KB)
    short8 ah[2], al[2];
    #pragma unroll
    for (int s = 0; s < 2; s++){
      size_t aoff = (((size_t)(kt*4 + g)) * 384 + (wo + s*16 + r)) * 8;
      ah[s] = *(const short8*)(Wkh + aoff);
      al[s] = *(const short8*)(Wkl + aoff);
    }
    #pragma unroll
    for (int nt = 0; nt < 4; nt++){
      short8 bh = *(const short8*)&sB[buf][0][g][wnl + nt*16 + r][0];
      short8 bl = *(const short8*)&sB[buf][1][g][wnl + nt*16 + r][0];
      #pragma unroll
      for (int s = 0; s < 2; s++){
        acc[s][nt] = __builtin_amdgcn_mfma_f32_16x16x32_bf16(ah[s], bh, acc[s][nt], 0, 0, 0);
        acc[s][nt] = __builtin_amdgcn_mfma_f32_16x16x32_bf16(ah[s], bl, acc[s][nt], 0, 0, 0);
        acc[s][nt] = __builtin_amdgcn_mfma_f32_16x16x32_bf16(al[s], bh, acc[s][nt], 0, 0, 0);
      }
    }
    // end of this e's GEMM: fold D_e * H[o,e,n] into dot
    if (kt == 10){
      #pragma unroll
      for (int s = 0; s < 2; s++){
        #pragma unroll
        for (int j = 0; j < 4; j++){
          int o = wo + s*16 + g*4 + j;
          if (o < 341){
            size_t hb = ((((size_t)(b*3 + e))*48 + (o >> 3)) * 2048) * 8 + (o & 7);
            #pragma unroll
            for (int nt = 0; nt < 4; nt++){
              int n = n0 + wnl + nt*16 + r;
              float v = bf2f(Hkh[hb + (size_t)n*8]) + bf2f(Hkl[hb + (size_t)n*8]);
              dotv[s][nt][j] += acc[s][nt][j] * v;
            }
          }
        }
      }
    }
    __syncthreads();
  }
  // packed argmax over n: reduce across nt (in-lane) and r (across 16 lanes)
  #pragma unroll
  for (int s = 0; s < 2; s++){
    #pragma unroll
    for (int j = 0; j < 4; j++){
      int o = wo + s*16 + g*4 + j;
      unsigned long long best = 0;
      #pragma unroll
      for (int nt = 0; nt < 4; nt++){
        int n = n0 + wnl + nt*16 + r;
        unsigned long long pk = ((unsigned long long)ordf(dotv[s][nt][j]) << 32) | (unsigned)(2047 - n);
        if (pk > best) best = pk;
      }
      #pragma unroll
      for (int st = 1; st < 16; st <<= 1){
        unsigned long long ob = __shfl_xor(best, st, 64);
        if (ob > best) best = ob;
      }
      if (r == 0 && o < 341) atomicMax(&packed[b*341 + o], best);
    }
  }
}

__global__ void pool_gather(const unsigned long long* __restrict__ packed,
                            const unsigned short* __restrict__ Hkh, const unsigned short* __restrict__ Hkl,
                            float* __restrict__ pooled){
  int t = blockIdx.x * 256 + threadIdx.x;
  if (t >= BATCH * 341) return;
  int n = 2047 - (int)(packed[t] & 0xffffffffu);
  int b = t / 341, o = t % 341;
  #pragma unroll
  for (int e = 0; e < 3; e++){
    size_t hb = ((((size_t)(b*3 + e))*48 + (o >> 3)) * 2048 + n) * 8 + (o & 7);
    pooled[t*3 + e] = bf2f(Hkh[hb]) + bf2f(Hkl[hb]);
  }
}

// -------- fully-connected VN layer (B=8 pixels, per-channel bn over B) -----------------
__global__ __launch_bounds__(64) void flayer(const float* __restrict__ in, const float* __restrict__ Wf,
    const float* __restrict__ Wd, float* __restrict__ out, int Cin, int Co){
  int o = blockIdx.x, lane = threadIdx.x;
  float pv[24], dv[24];
  #pragma unroll
  for (int be = 0; be < 24; be++){ pv[be] = 0.f; dv[be] = 0.f; }
  for (int c = lane; c < Cin; c += 64){
    float wf = Wf[o*Cin + c], wd = Wd[o*Cin + c];
    #pragma unroll
    for (int bb = 0; bb < 8; bb++){
      #pragma unroll
      for (int e = 0; e < 3; e++){
        float hv = in[(bb*Cin + c)*3 + e];
        pv[bb*3+e] = fmaf(wf, hv, pv[bb*3+e]);
        dv[bb*3+e] = fmaf(wd, hv, dv[bb*3+e]);
      }
    }
  }
  #pragma unroll
  for (int be = 0; be < 24; be++){
    #pragma unroll
    for (int st = 1; st < 64; st <<= 1){
      pv[be] += __shfl_xor(pv[be], st, 64);
      dv[be] += __shfl_xor(dv[be], st, 64);
    }
  }
  float nm[8], dotb[8], dsqb[8];
  float mean = 0.f;
  #pragma unroll
  for (int bb = 0; bb < 8; bb++){
    nm[bb] = sqrtf(pv[bb*3]*pv[bb*3] + pv[bb*3+1]*pv[bb*3+1] + pv[bb*3+2]*pv[bb*3+2]) + EPSF;
    mean += nm[bb];
  }
  mean *= 0.125f;
  float var = 0.f;
  #pragma unroll
  for (int bb = 0; bb < 8; bb++){ float dvv = nm[bb] - mean; var += dvv * dvv; }
  var *= 0.125f;
  float istd = 1.f / sqrtf(var + BNEPS);
  #pragma unroll
  for (int bb = 0; bb < 8; bb++){
    float f = (nm[bb] - mean) * istd / nm[bb];
    dotb[bb] = f * (pv[bb*3]*dv[bb*3] + pv[bb*3+1]*dv[bb*3+1] + pv[bb*3+2]*dv[bb*3+2]);
    dsqb[bb] = dv[bb*3]*dv[bb*3] + dv[bb*3+1]*dv[bb*3+1] + dv[bb*3+2]*dv[bb*3+2];
  }
  #pragma unroll
  for (int be = 0; be < 24; be++){
    if (lane == be){
      int bb = be / 3;
      float f = (nm[bb] - mean) * istd / nm[bb];
      float pe = pv[be] * f;
      float t = dotb[bb] / (dsqb[bb] + EPSF);
      float res = (dotb[bb] >= 0.f) ? pe : fmaf(-t, dv[be], pe);
      out[(bb*Co + o)*3 + (be % 3)] = res;
    }
  }
}

__global__ void final_lin(const float* __restrict__ in, const float* __restrict__ W, float* __restrict__ out){
  int t = threadIdx.x;
  if (t >= 72) return;
  int b = t / 9, o = (t % 9) / 3, e = t % 3;
  float s = 0.f;
  for (int c = 0; c < 85; c++) s = fmaf(W[o*85 + c], in[(b*85 + c)*3 + e], s);
  out[t] = s;
}

// --------------------------------- launcher -------------------------------------------
extern "C" void kernel_launch(void* const* d_in, const int* in_sizes, int n_in,
                              void* d_out, int out_size, void* d_ws, size_t ws_size,
                              hipStream_t stream){
  const float* x   = (const float*)d_in[0];
  const float* Wpf = (const float*)d_in[1];
  const float* Wpd = (const float*)d_in[2];
  const float* Wg  = (const float*)d_in[3];
  const float* W1f = (const float*)d_in[4];
  const float* W1d = (const float*)d_in[5];
  const float* W2f = (const float*)d_in[6];
  const float* W2d = (const float*)d_in[7];
  const float* W3f = (const float*)d_in[8];
  const float* W3d = (const float*)d_in[9];
  const float* Wpool = (const float*)d_in[10];
  const float* Wf1f = (const float*)d_in[11];
  const float* Wf1d = (const float*)d_in[12];
  const float* Wf2f = (const float*)d_in[13];
  const float* Wf2d = (const float*)d_in[14];
  const float* Wf3  = (const float*)d_in[15];
  float* out = (float*)d_out;

  char* ws = (char*)d_ws;
  size_t off = 0;
  int*   idx = (int*)(ws + off);              off += (size_t)BATCH*NP*KNN*4;
  float* h1  = (float*)(ws + off);            off += (size_t)BATCH*21*3*NP*4;
  float* h2  = (float*)(ws + off);            off += (size_t)BATCH*21*3*NP*4;
  float* h3  = (float*)(ws + off);            off += (size_t)BATCH*42*3*NP*4;
  unsigned short* Hkh = (unsigned short*)(ws + off); off += (size_t)BATCH*3*48*NP*8*2;
  unsigned short* Hkl = (unsigned short*)(ws + off); off += (size_t)BATCH*3*48*NP*8*2;
  unsigned short* Wkh = (unsigned short*)(ws + off); off += (size_t)44*384*8*2;
  unsigned short* Wkl = (unsigned short*)(ws + off); off += (size_t)44*384*8*2;
  char*  zbase = ws + off;
  double* sums_gf = (double*)(ws + off);      off += 8192;
  double* sums_l1 = (double*)(ws + off);      off += 8192;
  double* sums_l2 = (double*)(ws + off);      off += 8192;
  double* sums_l3 = (double*)(ws + off);      off += 8192;
  unsigned long long* packed = (unsigned long long*)(ws + off); off += 24576;
  size_t zbytes = (ws + off) - zbase;
  float* mi_gf = (float*)(ws + off);          off += 1024;
  float* mi_l1 = (float*)(ws + off);          off += 1024;
  float* mi_l2 = (float*)(ws + off);          off += 1024;
  float* mi_l3 = (float*)(ws + off);          off += 4096;
  float* pooled = (float*)(ws + off);         off += (size_t)BATCH*341*3*4 + 32;
  float* h5 = (float*)(ws + off);             off += (size_t)BATCH*170*3*4 + 32;
  float* h6 = (float*)(ws + off);             off += (size_t)BATCH*85*3*4 + 32;

  hipMemsetAsync(zbase, 0, zbytes, stream);

  knn_kernel<<<BATCH*NP/4, 256, 0, stream>>>(x, idx);
  wk_kernel<<<(44*384*8 + 255)/256, 256, 0, stream>>>(Wpool, Wkh, Wkl);

  gf_stats<<<256, 256, 0, stream>>>(x, idx, Wpf, sums_gf);
  finalize_stats<<<1, 64, 0, stream>>>(sums_gf, mi_gf, 21, 1.0 / (double)(BATCH*NP*KNN));
  gf_applypool<<<BATCH*NP/4, 256, 0, stream>>>(x, idx, Wpf, Wpd, Wg, mi_gf, h1);

  layer_stats<21><<<dim3(64,3), 256, 0, stream>>>(h1, W1f, sums_l1, 21, 7);
  finalize_stats<<<1, 64, 0, stream>>>(sums_l1, mi_l1, 21, 1.0 / (double)(BATCH*NP));
  layer_apply<21><<<dim3(64,3), 256, 0, stream>>>(h1, W1f, W1d, mi_l1, h2, 21, 7);

  layer_stats<21><<<dim3(64,3), 256, 0, stream>>>(h2, W2f, sums_l2, 42, 14);
  finalize_stats<<<1, 64, 0, stream>>>(sums_l2, mi_l2, 42, 1.0 / (double)(BATCH*NP));
  layer_apply<21><<<dim3(64,3), 256, 0, stream>>>(h2, W2f, W2d, mi_l2, h3, 42, 14);

  layer_stats<42><<<dim3(64,8), 256, 0, stream>>>(h3, W3f, sums_l3, 341, 43);
  finalize_stats<<<6, 64, 0, stream>>>(sums_l3, mi_l3, 341, 1.0 / (double)(BATCH*NP));
  layer_apply_l3<<<dim3(64,8), 256, 0, stream>>>(h3, W3f, W3d, mi_l3, Hkh, Hkl);

  pool_mfma<<<dim3(16, 6, BATCH), 256, 0, stream>>>(Wkh, Wkl, Hkh, Hkl, packed);
  pool_gather<<<(BATCH*341 + 255)/256, 256, 0, stream>>>(packed, Hkh, Hkl, pooled);

  flayer<<<170, 64, 0, stream>>>(pooled, Wf1f, Wf1d, h5, 341, 170);
  flayer<<<85, 64, 0, stream>>>(h5, Wf2f, Wf2d, h6, 170, 85);
  final_lin<<<1, 128, 0, stream>>>(h6, Wf3, out);
}

// Round 4
// 735.181 us; speedup vs baseline: 1.6175x; 1.1187x over previous
//
#include <hip/hip_runtime.h>

#define NP 2048
#define BATCH 8
#define KNN 40
#define EPSF 1e-6f
#define BNEPS 1e-5f

typedef __attribute__((ext_vector_type(8))) short short8;
typedef __attribute__((ext_vector_type(4))) float f32x4;

__device__ __forceinline__ unsigned ordf(float v){
  unsigned u = __float_as_uint(v);
  return (u & 0x80000000u) ? ~u : (u | 0x80000000u);
}

__device__ __forceinline__ unsigned long long wmax64(unsigned long long v){
  #pragma unroll
  for (int s = 32; s > 0; s >>= 1){
    unsigned long long o = __shfl_xor(v, s, 64);
    v = (o > v) ? o : v;
  }
  return v;
}

// split fp32 -> bf16 hi (RNE) + bf16 lo (RNE of residual)
__device__ __forceinline__ void bsplit(float v, unsigned short &h, unsigned short &l){
  unsigned u = __float_as_uint(v);
  unsigned hu = (u + 0x7fffu + ((u >> 16) & 1u)) >> 16;
  h = (unsigned short)hu;
  float r = v - __uint_as_float(hu << 16);
  unsigned u2 = __float_as_uint(r);
  l = (unsigned short)((u2 + 0x7fffu + ((u2 >> 16) & 1u)) >> 16);
}

__device__ __forceinline__ float bf2f(unsigned short h){
  return __uint_as_float(((unsigned)h) << 16);
}

// ---------------- KNN: exact top-40 (nearest incl. self), tie -> lowest index ----------
__global__ __launch_bounds__(256) void knn_kernel(const float* __restrict__ x, int* __restrict__ idx){
  __shared__ float sx0[NP], sx1[NP], sx2[NP], sxx[NP];
  int tid = threadIdx.x;
  int w = tid >> 6, lane = tid & 63;
  int row = blockIdx.x * 4 + w;
  int b = row >> 11, i = row & 2047;
  const float* xb = x + b * 3 * NP;
  for (int t = tid; t < NP; t += 256){ sx0[t] = xb[t]; sx1[t] = xb[NP + t]; sx2[t] = xb[2*NP + t]; }
  __syncthreads();
  for (int t = tid; t < NP; t += 256){
    float a = sx0[t], c = sx1[t], d = sx2[t];
    sxx[t] = __fadd_rn(__fadd_rn(__fmul_rn(a,a), __fmul_rn(c,c)), __fmul_rn(d,d));
  }
  __syncthreads();
  float xi0 = sx0[i], xi1 = sx1[i], xi2 = sx2[i], xxi = sxx[i];
  float nd[32];
  unsigned long long s0 = 0, s1 = 0, s2 = 0, s3 = 0;
  #pragma unroll
  for (int m = 0; m < 32; m++){
    int j = m * 64 + lane;
    float dot = __fadd_rn(__fadd_rn(__fmul_rn(xi0, sx0[j]), __fmul_rn(xi1, sx1[j])), __fmul_rn(xi2, sx2[j]));
    float v = __fsub_rn(__fsub_rn(-xxi, __fmul_rn(-2.f, dot)), sxx[j]);
    nd[m] = v;
    unsigned long long pk = ((unsigned long long)ordf(v) << 32) | (unsigned)(2047 - j);
    if (pk > s3){
      if (pk > s2){ s3 = s2; if (pk > s1){ s2 = s1; if (pk > s0){ s1 = s0; s0 = pk; } else s1 = pk; } else s2 = pk; }
      else s3 = pk;
    }
  }
  unsigned long long lastPop = ~0ull;
  int* outp = idx + row * KNN;
  for (int kk = 0; kk < KNN; kk++){
    unsigned long long g = wmax64(s0);
    if (s0 == g){
      outp[kk] = 2047 - (int)(g & 0xffffffffu);
      lastPop = g;
      s0 = s1; s1 = s2; s2 = s3; s3 = 0;
      if (s0 == 0){
        unsigned long long best = 0;
        #pragma unroll
        for (int m = 0; m < 32; m++){
          int j = m * 64 + lane;
          unsigned long long pk = ((unsigned long long)ordf(nd[m]) << 32) | (unsigned)(2047 - j);
          if (pk < lastPop && pk > best) best = pk;
        }
        s0 = best;
      }
    }
  }
}

// ------------- graph-feature layer: stats pass (p-norm sums per channel, 21 ch) --------
__global__ __launch_bounds__(256) void gf_stats(const float* __restrict__ x, const int* __restrict__ idx,
                                                const float* __restrict__ Wf, double* __restrict__ sums){
  int tid0 = blockIdx.x * 256 + threadIdx.x;
  float s[21], q[21];
  #pragma unroll
  for (int o = 0; o < 21; o++){ s[o] = 0.f; q[o] = 0.f; }
  for (int pix = tid0; pix < BATCH * NP * KNN; pix += 256 * 256){
    int rem = pix / KNN;
    int n = rem & 2047, b = rem >> 11;
    int j = idx[pix];
    const float* xb = x + b * 3 * NP;
    float c0 = xb[n], c1 = xb[NP + n], c2 = xb[2*NP + n];
    float a0 = xb[j], a1 = xb[NP + j], a2 = xb[2*NP + j];
    float r0 = a0 - c0, r1 = a1 - c1, r2 = a2 - c2;
    float g0 = a1*c2 - a2*c1, g1 = a2*c0 - a0*c2, g2 = a0*c1 - a1*c0;
    #pragma unroll
    for (int o = 0; o < 21; o++){
      float w0 = Wf[o*3], w1 = Wf[o*3+1], w2 = Wf[o*3+2];
      float p0 = w0*r0 + w1*c0 + w2*g0;
      float p1 = w0*r1 + w1*c1 + w2*g1;
      float p2 = w0*r2 + w1*c2 + w2*g2;
      float nm = sqrtf(p0*p0 + p1*p1 + p2*p2) + EPSF;
      s[o] += nm; q[o] += nm * nm;
    }
  }
  __shared__ float bs[4][42];
  int w = threadIdx.x >> 6;
  #pragma unroll
  for (int o = 0; o < 21; o++){
    float a = s[o], bb = q[o];
    #pragma unroll
    for (int st = 1; st < 64; st <<= 1){ a += __shfl_xor(a, st, 64); bb += __shfl_xor(bb, st, 64); }
    if ((threadIdx.x & 63) == 0){ bs[w][o] = a; bs[w][21 + o] = bb; }
  }
  __syncthreads();
  if (threadIdx.x < 42){
    float tot = bs[0][threadIdx.x] + bs[1][threadIdx.x] + bs[2][threadIdx.x] + bs[3][threadIdx.x];
    int o = threadIdx.x % 21, sq = threadIdx.x / 21;
    atomicAdd(&sums[2*o + sq], (double)tot);
  }
}

// -------- graph-feature layer: apply bn+lrelu, then max-pool over K (fused) ------------
__global__ __launch_bounds__(256) void gf_applypool(const float* __restrict__ x, const int* __restrict__ idx,
    const float* __restrict__ Wf, const float* __restrict__ Wd, const float* __restrict__ Wg,
    const float* __restrict__ mi, float* __restrict__ h1){
  int w = threadIdx.x >> 6, lane = threadIdx.x & 63;
  int pix = blockIdx.x * 4 + w;
  int n = pix & 2047, b = pix >> 11;
  const float* xb = x + b * 3 * NP;
  float c0 = xb[n], c1 = xb[NP + n], c2 = xb[2*NP + n];
  int j = (lane < KNN) ? idx[pix * KNN + lane] : n;
  float a0 = xb[j], a1 = xb[NP + j], a2 = xb[2*NP + j];
  float r0 = a0 - c0, r1 = a1 - c1, r2 = a2 - c2;
  float g0 = a1*c2 - a2*c1, g1 = a2*c0 - a0*c2, g2 = a0*c1 - a1*c0;
  float h[21][3];
  #pragma unroll
  for (int o = 0; o < 21; o++){
    float w0 = Wf[o*3], w1 = Wf[o*3+1], w2 = Wf[o*3+2];
    float p0 = w0*r0 + w1*c0 + w2*g0;
    float p1 = w0*r1 + w1*c1 + w2*g1;
    float p2 = w0*r2 + w1*c2 + w2*g2;
    float nm = sqrtf(p0*p0 + p1*p1 + p2*p2) + EPSF;
    float f = (nm - mi[2*o]) * mi[2*o+1] / nm;
    p0 *= f; p1 *= f; p2 *= f;
    float v0 = Wd[o*3], v1 = Wd[o*3+1], v2 = Wd[o*3+2];
    float d0 = v0*r0 + v1*c0 + v2*g0;
    float d1 = v0*r1 + v1*c1 + v2*g1;
    float d2 = v0*r2 + v1*c2 + v2*g2;
    float dot = p0*d0 + p1*d1 + p2*d2;
    float dsq = d0*d0 + d1*d1 + d2*d2;
    float t = dot / (dsq + EPSF);
    h[o][0] = (dot >= 0.f) ? p0 : fmaf(-t, d0, p0);
    h[o][1] = (dot >= 0.f) ? p1 : fmaf(-t, d1, p1);
    h[o][2] = (dot >= 0.f) ? p2 : fmaf(-t, d2, p2);
  }
  #pragma unroll
  for (int o = 0; o < 21; o++){
    float q0 = 0.f, q1 = 0.f, q2 = 0.f;
    #pragma unroll
    for (int c = 0; c < 21; c++){
      float wg = Wg[o*21 + c];
      q0 = fmaf(wg, h[c][0], q0); q1 = fmaf(wg, h[c][1], q1); q2 = fmaf(wg, h[c][2], q2);
    }
    float dp = q0*h[o][0] + q1*h[o][1] + q2*h[o][2];
    float m = (lane < KNN) ? dp : -INFINITY;
    #pragma unroll
    for (int s = 32; s > 0; s >>= 1) m = fmaxf(m, __shfl_xor(m, s, 64));
    unsigned long long msk = __ballot(lane < KNN && dp == m);
    int wl = __ffsll(msk) - 1;
    float o0 = __shfl(h[o][0], wl, 64);
    float o1 = __shfl(h[o][1], wl, 64);
    float o2 = __shfl(h[o][2], wl, 64);
    if (lane == 0){
      float* dst = h1 + (size_t)((b*21 + o)*3) * NP + n;
      dst[0] = o0; dst[NP] = o1; dst[2*NP] = o2;
    }
  }
}

// ---------------- generic VN layer: stats + apply (thread per (b,n)) ------------------
template<int CIN>
__global__ __launch_bounds__(256) void layer_stats(const float* __restrict__ hin, const float* __restrict__ Wf,
                                                   double* __restrict__ sums, int Co, int oPerG){
  int tid = blockIdx.x * 256 + threadIdx.x;
  int n = tid & 2047, b = tid >> 11;
  int o0 = blockIdx.y * oPerG;
  int o1 = o0 + oPerG; if (o1 > Co) o1 = Co;
  float h[CIN*3];
  #pragma unroll
  for (int c = 0; c < CIN; c++){
    #pragma unroll
    for (int e = 0; e < 3; e++) h[c*3+e] = hin[(size_t)((b*CIN + c)*3 + e) * NP + n];
  }
  int lane = threadIdx.x & 63;
  for (int o = o0; o < o1; o++){
    float p0 = 0.f, p1 = 0.f, p2 = 0.f;
    #pragma unroll
    for (int c = 0; c < CIN; c++){
      float wv = Wf[o*CIN + c];
      p0 = fmaf(wv, h[c*3], p0); p1 = fmaf(wv, h[c*3+1], p1); p2 = fmaf(wv, h[c*3+2], p2);
    }
    float nm = sqrtf(p0*p0 + p1*p1 + p2*p2) + EPSF;
    float v1 = nm, v2 = nm * nm;
    #pragma unroll
    for (int st = 1; st < 64; st <<= 1){ v1 += __shfl_xor(v1, st, 64); v2 += __shfl_xor(v2, st, 64); }
    if (lane == 0){ atomicAdd(&sums[2*o], (double)v1); atomicAdd(&sums[2*o+1], (double)v2); }
  }
}

template<int CIN>
__global__ __launch_bounds__(256) void layer_apply(const float* __restrict__ hin, const float* __restrict__ Wf,
    const float* __restrict__ Wd, const float* __restrict__ mi, float* __restrict__ hout, int Co, int oPerG){
  int tid = blockIdx.x * 256 + threadIdx.x;
  int n = tid & 2047, b = tid >> 11;
  int o0 = blockIdx.y * oPerG;
  int o1 = o0 + oPerG; if (o1 > Co) o1 = Co;
  float h[CIN*3];
  #pragma unroll
  for (int c = 0; c < CIN; c++){
    #pragma unroll
    for (int e = 0; e < 3; e++) h[c*3+e] = hin[(size_t)((b*CIN + c)*3 + e) * NP + n];
  }
  for (int o = o0; o < o1; o++){
    float p0 = 0.f, p1 = 0.f, p2 = 0.f, d0 = 0.f, d1 = 0.f, d2 = 0.f;
    #pragma unroll
    for (int c = 0; c < CIN; c++){
      float wv = Wf[o*CIN + c], vv = Wd[o*CIN + c];
      p0 = fmaf(wv, h[c*3], p0); p1 = fmaf(wv, h[c*3+1], p1); p2 = fmaf(wv, h[c*3+2], p2);
      d0 = fmaf(vv, h[c*3], d0); d1 = fmaf(vv, h[c*3+1], d1); d2 = fmaf(vv, h[c*3+2], d2);
    }
    float nm = sqrtf(p0*p0 + p1*p1 + p2*p2) + EPSF;
    float f = (nm - mi[2*o]) * mi[2*o+1] / nm;
    p0 *= f; p1 *= f; p2 *= f;
    float dot = p0*d0 + p1*d1 + p2*d2;
    float dsq = d0*d0 + d1*d1 + d2*d2;
    float t = dot / (dsq + EPSF);
    float r0 = (dot >= 0.f) ? p0 : fmaf(-t, d0, p0);
    float r1 = (dot >= 0.f) ? p1 : fmaf(-t, d1, p1);
    float r2 = (dot >= 0.f) ? p2 : fmaf(-t, d2, p2);
    float* dst = hout + (size_t)((b*Co + o)*3) * NP + n;
    dst[0] = r0; dst[NP] = r1; dst[2*NP] = r2;
  }
}

// ------- last VN layer (42->341): apply + write k-packed bf16 hi/lo (for MFMA pool) ----
// Hk layout: [b][e][kb=0..47][n=0..2047][j=0..7]  (channel c = kb*8+j), 16B granules
__global__ __launch_bounds__(256) void layer_apply_l3(const float* __restrict__ hin, const float* __restrict__ Wf,
    const float* __restrict__ Wd, const float* __restrict__ mi,
    unsigned short* __restrict__ Hkh, unsigned short* __restrict__ Hkl){
  int tid = blockIdx.x * 256 + threadIdx.x;
  int n = tid & 2047, b = tid >> 11;
  int o0 = blockIdx.y * 48;
  float h[126];
  #pragma unroll
  for (int c = 0; c < 42; c++){
    #pragma unroll
    for (int e = 0; e < 3; e++) h[c*3+e] = hin[(size_t)((b*42 + c)*3 + e) * NP + n];
  }
  for (int gq = 0; gq < 6; gq++){
    unsigned ph[3][4], pl[3][4];
    #pragma unroll
    for (int j = 0; j < 8; j++){
      int o = o0 + gq*8 + j;
      float r0 = 0.f, r1 = 0.f, r2 = 0.f;
      if (o < 341){
        float p0=0.f,p1=0.f,p2=0.f,d0=0.f,d1=0.f,d2=0.f;
        #pragma unroll
        for (int c = 0; c < 42; c++){
          float wv = Wf[o*42 + c], vv = Wd[o*42 + c];
          p0 = fmaf(wv, h[c*3], p0); p1 = fmaf(wv, h[c*3+1], p1); p2 = fmaf(wv, h[c*3+2], p2);
          d0 = fmaf(vv, h[c*3], d0); d1 = fmaf(vv, h[c*3+1], d1); d2 = fmaf(vv, h[c*3+2], d2);
        }
        float nm = sqrtf(p0*p0 + p1*p1 + p2*p2) + EPSF;
        float f = (nm - mi[2*o]) * mi[2*o+1] / nm;
        p0 *= f; p1 *= f; p2 *= f;
        float dot = p0*d0 + p1*d1 + p2*d2;
        float dsq = d0*d0 + d1*d1 + d2*d2;
        float t = dot / (dsq + EPSF);
        r0 = (dot >= 0.f) ? p0 : fmaf(-t, d0, p0);
        r1 = (dot >= 0.f) ? p1 : fmaf(-t, d1, p1);
        r2 = (dot >= 0.f) ? p2 : fmaf(-t, d2, p2);
      }
      unsigned short hh, ll;
      bsplit(r0, hh, ll);
      if (!(j & 1)){ ph[0][j>>1] = hh; pl[0][j>>1] = ll; }
      else { ph[0][j>>1] |= ((unsigned)hh) << 16; pl[0][j>>1] |= ((unsigned)ll) << 16; }
      bsplit(r1, hh, ll);
      if (!(j & 1)){ ph[1][j>>1] = hh; pl[1][j>>1] = ll; }
      else { ph[1][j>>1] |= ((unsigned)hh) << 16; pl[1][j>>1] |= ((unsigned)ll) << 16; }
      bsplit(r2, hh, ll);
      if (!(j & 1)){ ph[2][j>>1] = hh; pl[2][j>>1] = ll; }
      else { ph[2][j>>1] |= ((unsigned)hh) << 16; pl[2][j>>1] |= ((unsigned)ll) << 16; }
    }
    #pragma unroll
    for (int e = 0; e < 3; e++){
      size_t base = ((((size_t)(b*3 + e))*48 + (o0 >> 3) + gq) * 2048 + n) * 8;
      *(uint4*)(Hkh + base) = make_uint4(ph[e][0], ph[e][1], ph[e][2], ph[e][3]);
      *(uint4*)(Hkl + base) = make_uint4(pl[e][0], pl[e][1], pl[e][2], pl[e][3]);
    }
  }
}

__global__ void finalize_stats(const double* __restrict__ sums, float* __restrict__ mi, int Co, double invM){
  int o = blockIdx.x * 64 + threadIdx.x;
  if (o >= Co) return;
  double m = sums[2*o] * invM;
  double v = sums[2*o+1] * invM - m * m;
  if (v < 0.0) v = 0.0;
  mi[2*o] = (float)m;
  mi[2*o+1] = (float)(1.0 / sqrt(v + (double)BNEPS));
}

// ------- split W_pool into k-packed bf16 hi/lo: Wk[cb=0..43][o=0..383][j=0..7] ---------
__global__ __launch_bounds__(256) void wk_kernel(const float* __restrict__ Wp,
    unsigned short* __restrict__ Wkh, unsigned short* __restrict__ Wkl){
  int t = blockIdx.x * 256 + threadIdx.x;
  if (t >= 44*384*8) return;
  int j = t & 7, o = (t >> 3) % 384, cb = t / (384*8);
  int c = cb*8 + j;
  float v = (c < 341 && o < 341) ? Wp[o*341 + c] : 0.f;
  unsigned short h, l;
  bsplit(v, h, l);
  Wkh[t] = h; Wkl[t] = l;
}

// ------------- pool over N via split-bf16 MFMA: D = Wpool @ H; dot; argmax -------------
// grid (32 n-tiles, 3 o-tiles, 8 b), 256 thr. Block tile 128(o) x 64(n).
// Wave w: o rows [o0+w*32, +32). 16x16x32 bf16 MFMA, 3-term split.
// dot-fold H values captured from LDS at kt == (wave o-range)>>5 -> no global re-read.
__global__ __launch_bounds__(256) void pool_mfma(const unsigned short* __restrict__ Wkh,
    const unsigned short* __restrict__ Wkl, const unsigned short* __restrict__ Hkh,
    const unsigned short* __restrict__ Hkl, unsigned long long* __restrict__ packed){
  __shared__ unsigned short sB[2][2][4][64][8];   // [buf][hi/lo][kb][n][j] = 16 KB
  const int b = blockIdx.z, o0 = blockIdx.y * 128, n0 = blockIdx.x * 64;
  const int t = threadIdx.x, w = t >> 6, l = t & 63;
  const int wo = o0 + w * 32;              // wave o base (32 rows)
  const int r = l & 15, g = l >> 4;
  const int skb = t >> 6, sn = t & 63;     // staging: 4 kb x 64 n = 256 thr, 16B each
  const int ktw = wo >> 5;                 // k-tile whose channels == this wave's o-range

  f32x4 acc[2][4], dotv[2][4], hval[2][4];
  #pragma unroll
  for (int s = 0; s < 2; s++)
    #pragma unroll
    for (int nt = 0; nt < 4; nt++){ dotv[s][nt] = (f32x4)0.f; hval[s][nt] = (f32x4)0.f; }

  auto gsrc = [&](const unsigned short* base, int e, int kt) -> const uint4* {
    return (const uint4*)(base + ((((size_t)(b*3 + e))*48 + (size_t)(kt*4 + skb)) * 2048 + n0 + sn) * 8);
  };

  uint4 rg[2];
  rg[0] = *gsrc(Hkh, 0, 0);
  rg[1] = *gsrc(Hkl, 0, 0);

  for (int ek = 0; ek < 33; ek++){
    const int e = ek / 11, kt = ek - e*11, buf = ek & 1;
    // write staged regs into LDS
    *(uint4*)&sB[buf][0][skb][sn][0] = rg[0];
    *(uint4*)&sB[buf][1][skb][sn][0] = rg[1];
    __syncthreads();
    // prefetch next k-tile into regs (overlaps MFMA below)
    if (ek < 32){
      int e2 = (ek+1) / 11, kt2 = (ek+1) - e2*11;
      rg[0] = *gsrc(Hkh, e2, kt2);
      rg[1] = *gsrc(Hkl, e2, kt2);
    }
    if (kt == 0){
      #pragma unroll
      for (int s = 0; s < 2; s++)
        #pragma unroll
        for (int nt = 0; nt < 4; nt++) acc[s][nt] = (f32x4)0.f;
    }
    // A fragments straight from global (L2-hot, 540 KB total)
    short8 ah[2], al[2];
    #pragma unroll
    for (int s = 0; s < 2; s++){
      size_t aoff = (((size_t)(kt*4 + g)) * 384 + (wo + s*16 + r)) * 8;
      ah[s] = *(const short8*)(Wkh + aoff);
      al[s] = *(const short8*)(Wkl + aoff);
    }
    #pragma unroll
    for (int nt = 0; nt < 4; nt++){
      short8 bh = *(const short8*)&sB[buf][0][g][nt*16 + r][0];
      short8 bl = *(const short8*)&sB[buf][1][g][nt*16 + r][0];
      #pragma unroll
      for (int s = 0; s < 2; s++){
        acc[s][nt] = __builtin_amdgcn_mfma_f32_16x16x32_bf16(ah[s], bh, acc[s][nt], 0, 0, 0);
        acc[s][nt] = __builtin_amdgcn_mfma_f32_16x16x32_bf16(ah[s], bl, acc[s][nt], 0, 0, 0);
        acc[s][nt] = __builtin_amdgcn_mfma_f32_16x16x32_bf16(al[s], bh, acc[s][nt], 0, 0, 0);
      }
    }
    // capture this wave's H[o][n] values from the staged tile (for the dot-fold)
    if (kt == ktw){
      #pragma unroll
      for (int s = 0; s < 2; s++){
        #pragma unroll
        for (int jj = 0; jj < 4; jj++){
          int oin = s*16 + g*4 + jj;   // o - kt*32, in [0,32)
          #pragma unroll
          for (int nt = 0; nt < 4; nt++){
            hval[s][nt][jj] = bf2f(sB[buf][0][oin>>3][nt*16 + r][oin&7])
                            + bf2f(sB[buf][1][oin>>3][nt*16 + r][oin&7]);
          }
        }
      }
    }
    __syncthreads();
    // end of this e's GEMM: fold D_e * H[o,e,n] into dot
    if (kt == 10){
      #pragma unroll
      for (int s = 0; s < 2; s++)
        #pragma unroll
        for (int nt = 0; nt < 4; nt++)
          #pragma unroll
          for (int jj = 0; jj < 4; jj++)
            dotv[s][nt][jj] += acc[s][nt][jj] * hval[s][nt][jj];
    }
  }
  // packed argmax over n: reduce across nt (in-lane) and r (across 16 lanes)
  #pragma unroll
  for (int s = 0; s < 2; s++){
    #pragma unroll
    for (int j = 0; j < 4; j++){
      int o = wo + s*16 + g*4 + j;
      unsigned long long best = 0;
      #pragma unroll
      for (int nt = 0; nt < 4; nt++){
        int n = n0 + nt*16 + r;
        unsigned long long pk = ((unsigned long long)ordf(dotv[s][nt][j]) << 32) | (unsigned)(2047 - n);
        if (pk > best) best = pk;
      }
      #pragma unroll
      for (int st = 1; st < 16; st <<= 1){
        unsigned long long ob = __shfl_xor(best, st, 64);
        if (ob > best) best = ob;
      }
      if (r == 0 && o < 341) atomicMax(&packed[b*341 + o], best);
    }
  }
}

__global__ void pool_gather(const unsigned long long* __restrict__ packed,
                            const unsigned short* __restrict__ Hkh, const unsigned short* __restrict__ Hkl,
                            float* __restrict__ pooled){
  int t = blockIdx.x * 256 + threadIdx.x;
  if (t >= BATCH * 341) return;
  int n = 2047 - (int)(packed[t] & 0xffffffffu);
  int b = t / 341, o = t % 341;
  #pragma unroll
  for (int e = 0; e < 3; e++){
    size_t hb = ((((size_t)(b*3 + e))*48 + (o >> 3)) * 2048 + n) * 8 + (o & 7);
    pooled[t*3 + e] = bf2f(Hkh[hb]) + bf2f(Hkl[hb]);
  }
}

// -------- fully-connected VN layer (B=8 pixels, per-channel bn over B) -----------------
__global__ __launch_bounds__(64) void flayer(const float* __restrict__ in, const float* __restrict__ Wf,
    const float* __restrict__ Wd, float* __restrict__ out, int Cin, int Co){
  int o = blockIdx.x, lane = threadIdx.x;
  float pv[24], dv[24];
  #pragma unroll
  for (int be = 0; be < 24; be++){ pv[be] = 0.f; dv[be] = 0.f; }
  for (int c = lane; c < Cin; c += 64){
    float wf = Wf[o*Cin + c], wd = Wd[o*Cin + c];
    #pragma unroll
    for (int bb = 0; bb < 8; bb++){
      #pragma unroll
      for (int e = 0; e < 3; e++){
        float hv = in[(bb*Cin + c)*3 + e];
        pv[bb*3+e] = fmaf(wf, hv, pv[bb*3+e]);
        dv[bb*3+e] = fmaf(wd, hv, dv[bb*3+e]);
      }
    }
  }
  #pragma unroll
  for (int be = 0; be < 24; be++){
    #pragma unroll
    for (int st = 1; st < 64; st <<= 1){
      pv[be] += __shfl_xor(pv[be], st, 64);
      dv[be] += __shfl_xor(dv[be], st, 64);
    }
  }
  float nm[8], dotb[8], dsqb[8];
  float mean = 0.f;
  #pragma unroll
  for (int bb = 0; bb < 8; bb++){
    nm[bb] = sqrtf(pv[bb*3]*pv[bb*3] + pv[bb*3+1]*pv[bb*3+1] + pv[bb*3+2]*pv[bb*3+2]) + EPSF;
    mean += nm[bb];
  }
  mean *= 0.125f;
  float var = 0.f;
  #pragma unroll
  for (int bb = 0; bb < 8; bb++){ float dvv = nm[bb] - mean; var += dvv * dvv; }
  var *= 0.125f;
  float istd = 1.f / sqrtf(var + BNEPS);
  #pragma unroll
  for (int bb = 0; bb < 8; bb++){
    float f = (nm[bb] - mean) * istd / nm[bb];
    dotb[bb] = f * (pv[bb*3]*dv[bb*3] + pv[bb*3+1]*dv[bb*3+1] + pv[bb*3+2]*dv[bb*3+2]);
    dsqb[bb] = dv[bb*3]*dv[bb*3] + dv[bb*3+1]*dv[bb*3+1] + dv[bb*3+2]*dv[bb*3+2];
  }
  #pragma unroll
  for (int be = 0; be < 24; be++){
    if (lane == be){
      int bb = be / 3;
      float f = (nm[bb] - mean) * istd / nm[bb];
      float pe = pv[be] * f;
      float t = dotb[bb] / (dsqb[bb] + EPSF);
      float res = (dotb[bb] >= 0.f) ? pe : fmaf(-t, dv[be], pe);
      out[(bb*Co + o)*3 + (be % 3)] = res;
    }
  }
}

__global__ void final_lin(const float* __restrict__ in, const float* __restrict__ W, float* __restrict__ out){
  int t = threadIdx.x;
  if (t >= 72) return;
  int b = t / 9, o = (t % 9) / 3, e = t % 3;
  float s = 0.f;
  for (int c = 0; c < 85; c++) s = fmaf(W[o*85 + c], in[(b*85 + c)*3 + e], s);
  out[t] = s;
}

// --------------------------------- launcher -------------------------------------------
extern "C" void kernel_launch(void* const* d_in, const int* in_sizes, int n_in,
                              void* d_out, int out_size, void* d_ws, size_t ws_size,
                              hipStream_t stream){
  const float* x   = (const float*)d_in[0];
  const float* Wpf = (const float*)d_in[1];
  const float* Wpd = (const float*)d_in[2];
  const float* Wg  = (const float*)d_in[3];
  const float* W1f = (const float*)d_in[4];
  const float* W1d = (const float*)d_in[5];
  const float* W2f = (const float*)d_in[6];
  const float* W2d = (const float*)d_in[7];
  const float* W3f = (const float*)d_in[8];
  const float* W3d = (const float*)d_in[9];
  const float* Wpool = (const float*)d_in[10];
  const float* Wf1f = (const float*)d_in[11];
  const float* Wf1d = (const float*)d_in[12];
  const float* Wf2f = (const float*)d_in[13];
  const float* Wf2d = (const float*)d_in[14];
  const float* Wf3  = (const float*)d_in[15];
  float* out = (float*)d_out;

  char* ws = (char*)d_ws;
  size_t off = 0;
  int*   idx = (int*)(ws + off);              off += (size_t)BATCH*NP*KNN*4;
  float* h1  = (float*)(ws + off);            off += (size_t)BATCH*21*3*NP*4;
  float* h2  = (float*)(ws + off);            off += (size_t)BATCH*21*3*NP*4;
  float* h3  = (float*)(ws + off);            off += (size_t)BATCH*42*3*NP*4;
  unsigned short* Hkh = (unsigned short*)(ws + off); off += (size_t)BATCH*3*48*NP*8*2;
  unsigned short* Hkl = (unsigned short*)(ws + off); off += (size_t)BATCH*3*48*NP*8*2;
  unsigned short* Wkh = (unsigned short*)(ws + off); off += (size_t)44*384*8*2;
  unsigned short* Wkl = (unsigned short*)(ws + off); off += (size_t)44*384*8*2;
  char*  zbase = ws + off;
  double* sums_gf = (double*)(ws + off);      off += 8192;
  double* sums_l1 = (double*)(ws + off);      off += 8192;
  double* sums_l2 = (double*)(ws + off);      off += 8192;
  double* sums_l3 = (double*)(ws + off);      off += 8192;
  unsigned long long* packed = (unsigned long long*)(ws + off); off += 24576;
  size_t zbytes = (ws + off) - zbase;
  float* mi_gf = (float*)(ws + off);          off += 1024;
  float* mi_l1 = (float*)(ws + off);          off += 1024;
  float* mi_l2 = (float*)(ws + off);          off += 1024;
  float* mi_l3 = (float*)(ws + off);          off += 4096;
  float* pooled = (float*)(ws + off);         off += (size_t)BATCH*341*3*4 + 32;
  float* h5 = (float*)(ws + off);             off += (size_t)BATCH*170*3*4 + 32;
  float* h6 = (float*)(ws + off);             off += (size_t)BATCH*85*3*4 + 32;

  hipMemsetAsync(zbase, 0, zbytes, stream);

  knn_kernel<<<BATCH*NP/4, 256, 0, stream>>>(x, idx);
  wk_kernel<<<(44*384*8 + 255)/256, 256, 0, stream>>>(Wpool, Wkh, Wkl);

  gf_stats<<<256, 256, 0, stream>>>(x, idx, Wpf, sums_gf);
  finalize_stats<<<1, 64, 0, stream>>>(sums_gf, mi_gf, 21, 1.0 / (double)(BATCH*NP*KNN));
  gf_applypool<<<BATCH*NP/4, 256, 0, stream>>>(x, idx, Wpf, Wpd, Wg, mi_gf, h1);

  layer_stats<21><<<dim3(64,3), 256, 0, stream>>>(h1, W1f, sums_l1, 21, 7);
  finalize_stats<<<1, 64, 0, stream>>>(sums_l1, mi_l1, 21, 1.0 / (double)(BATCH*NP));
  layer_apply<21><<<dim3(64,3), 256, 0, stream>>>(h1, W1f, W1d, mi_l1, h2, 21, 7);

  layer_stats<21><<<dim3(64,3), 256, 0, stream>>>(h2, W2f, sums_l2, 42, 14);
  finalize_stats<<<1, 64, 0, stream>>>(sums_l2, mi_l2, 42, 1.0 / (double)(BATCH*NP));
  layer_apply<21><<<dim3(64,3), 256, 0, stream>>>(h2, W2f, W2d, mi_l2, h3, 42, 14);

  layer_stats<42><<<dim3(64,8), 256, 0, stream>>>(h3, W3f, sums_l3, 341, 43);
  finalize_stats<<<6, 64, 0, stream>>>(sums_l3, mi_l3, 341, 1.0 / (double)(BATCH*NP));
  layer_apply_l3<<<dim3(64,8), 256, 0, stream>>>(h3, W3f, W3d, mi_l3, Hkh, Hkl);

  pool_mfma<<<dim3(32, 3, BATCH), 256, 0, stream>>>(Wkh, Wkl, Hkh, Hkl, packed);
  pool_gather<<<(BATCH*341 + 255)/256, 256, 0, stream>>>(packed, Hkh, Hkl, pooled);

  flayer<<<170, 64, 0, stream>>>(pooled, Wf1f, Wf1d, h5, 341, 170);
  flayer<<<85, 64, 0, stream>>>(h5, Wf2f, Wf2d, h6, 170, 85);
  final_lin<<<1, 128, 0, stream>>>(h6, Wf3, out);
}

// Round 5
// 547.088 us; speedup vs baseline: 2.1736x; 1.3438x over previous
//
#include <hip/hip_runtime.h>

#define NP 2048
#define BATCH 8
#define KNN 40
#define EPSF 1e-6f
#define BNEPS 1e-5f

typedef __attribute__((ext_vector_type(8))) short short8;
typedef __attribute__((ext_vector_type(4))) float f32x4;

__device__ __forceinline__ unsigned ordf(float v){
  unsigned u = __float_as_uint(v);
  return (u & 0x80000000u) ? ~u : (u | 0x80000000u);
}

__device__ __forceinline__ unsigned long long wmax64(unsigned long long v){
  #pragma unroll
  for (int s = 32; s > 0; s >>= 1){
    unsigned long long o = __shfl_xor(v, s, 64);
    v = (o > v) ? o : v;
  }
  return v;
}

// split fp32 -> bf16 hi (RNE) + bf16 lo (RNE of residual)
__device__ __forceinline__ void bsplit(float v, unsigned short &h, unsigned short &l){
  unsigned u = __float_as_uint(v);
  unsigned hu = (u + 0x7fffu + ((u >> 16) & 1u)) >> 16;
  h = (unsigned short)hu;
  float r = v - __uint_as_float(hu << 16);
  unsigned u2 = __float_as_uint(r);
  l = (unsigned short)((u2 + 0x7fffu + ((u2 >> 16) & 1u)) >> 16);
}

__device__ __forceinline__ float bf2f(unsigned short h){
  return __uint_as_float(((unsigned)h) << 16);
}

// ---------------- KNN: exact top-40 (nearest incl. self), tie -> lowest index ----------
__global__ __launch_bounds__(256) void knn_kernel(const float* __restrict__ x, int* __restrict__ idx){
  __shared__ float sx0[NP], sx1[NP], sx2[NP], sxx[NP];
  int tid = threadIdx.x;
  int w = tid >> 6, lane = tid & 63;
  int row = blockIdx.x * 4 + w;
  int b = row >> 11, i = row & 2047;
  const float* xb = x + b * 3 * NP;
  for (int t = tid; t < NP; t += 256){ sx0[t] = xb[t]; sx1[t] = xb[NP + t]; sx2[t] = xb[2*NP + t]; }
  __syncthreads();
  for (int t = tid; t < NP; t += 256){
    float a = sx0[t], c = sx1[t], d = sx2[t];
    sxx[t] = __fadd_rn(__fadd_rn(__fmul_rn(a,a), __fmul_rn(c,c)), __fmul_rn(d,d));
  }
  __syncthreads();
  float xi0 = sx0[i], xi1 = sx1[i], xi2 = sx2[i], xxi = sxx[i];
  float nd[32];
  unsigned long long s0 = 0, s1 = 0, s2 = 0, s3 = 0;
  #pragma unroll
  for (int m = 0; m < 32; m++){
    int j = m * 64 + lane;
    float dot = __fadd_rn(__fadd_rn(__fmul_rn(xi0, sx0[j]), __fmul_rn(xi1, sx1[j])), __fmul_rn(xi2, sx2[j]));
    float v = __fsub_rn(__fsub_rn(-xxi, __fmul_rn(-2.f, dot)), sxx[j]);
    nd[m] = v;
    unsigned long long pk = ((unsigned long long)ordf(v) << 32) | (unsigned)(2047 - j);
    if (pk > s3){
      if (pk > s2){ s3 = s2; if (pk > s1){ s2 = s1; if (pk > s0){ s1 = s0; s0 = pk; } else s1 = pk; } else s2 = pk; }
      else s3 = pk;
    }
  }
  unsigned long long lastPop = ~0ull;
  int* outp = idx + row * KNN;
  for (int kk = 0; kk < KNN; kk++){
    unsigned long long g = wmax64(s0);
    if (s0 == g){
      outp[kk] = 2047 - (int)(g & 0xffffffffu);
      lastPop = g;
      s0 = s1; s1 = s2; s2 = s3; s3 = 0;
      if (s0 == 0){
        unsigned long long best = 0;
        #pragma unroll
        for (int m = 0; m < 32; m++){
          int j = m * 64 + lane;
          unsigned long long pk = ((unsigned long long)ordf(nd[m]) << 32) | (unsigned)(2047 - j);
          if (pk < lastPop && pk > best) best = pk;
        }
        s0 = best;
      }
    }
  }
}

// ------------- graph-feature layer: stats pass (p-norm sums per channel, 21 ch) --------
__global__ __launch_bounds__(256) void gf_stats(const float* __restrict__ x, const int* __restrict__ idx,
                                                const float* __restrict__ Wf, double* __restrict__ sums){
  int tid0 = blockIdx.x * 256 + threadIdx.x;
  float s[21], q[21];
  #pragma unroll
  for (int o = 0; o < 21; o++){ s[o] = 0.f; q[o] = 0.f; }
  for (int pix = tid0; pix < BATCH * NP * KNN; pix += 256 * 256){
    int rem = pix / KNN;
    int n = rem & 2047, b = rem >> 11;
    int j = idx[pix];
    const float* xb = x + b * 3 * NP;
    float c0 = xb[n], c1 = xb[NP + n], c2 = xb[2*NP + n];
    float a0 = xb[j], a1 = xb[NP + j], a2 = xb[2*NP + j];
    float r0 = a0 - c0, r1 = a1 - c1, r2 = a2 - c2;
    float g0 = a1*c2 - a2*c1, g1 = a2*c0 - a0*c2, g2 = a0*c1 - a1*c0;
    #pragma unroll
    for (int o = 0; o < 21; o++){
      float w0 = Wf[o*3], w1 = Wf[o*3+1], w2 = Wf[o*3+2];
      float p0 = w0*r0 + w1*c0 + w2*g0;
      float p1 = w0*r1 + w1*c1 + w2*g1;
      float p2 = w0*r2 + w1*c2 + w2*g2;
      float nm = sqrtf(p0*p0 + p1*p1 + p2*p2) + EPSF;
      s[o] += nm; q[o] += nm * nm;
    }
  }
  __shared__ float bs[4][42];
  int w = threadIdx.x >> 6;
  #pragma unroll
  for (int o = 0; o < 21; o++){
    float a = s[o], bb = q[o];
    #pragma unroll
    for (int st = 1; st < 64; st <<= 1){ a += __shfl_xor(a, st, 64); bb += __shfl_xor(bb, st, 64); }
    if ((threadIdx.x & 63) == 0){ bs[w][o] = a; bs[w][21 + o] = bb; }
  }
  __syncthreads();
  if (threadIdx.x < 42){
    float tot = bs[0][threadIdx.x] + bs[1][threadIdx.x] + bs[2][threadIdx.x] + bs[3][threadIdx.x];
    int o = threadIdx.x % 21, sq = threadIdx.x / 21;
    atomicAdd(&sums[2*o + sq], (double)tot);
  }
}

// -------- graph-feature layer: apply bn+lrelu, then max-pool over K (fused) ------------
__global__ __launch_bounds__(256) void gf_applypool(const float* __restrict__ x, const int* __restrict__ idx,
    const float* __restrict__ Wf, const float* __restrict__ Wd, const float* __restrict__ Wg,
    const float* __restrict__ mi, float* __restrict__ h1){
  int w = threadIdx.x >> 6, lane = threadIdx.x & 63;
  int pix = blockIdx.x * 4 + w;
  int n = pix & 2047, b = pix >> 11;
  const float* xb = x + b * 3 * NP;
  float c0 = xb[n], c1 = xb[NP + n], c2 = xb[2*NP + n];
  int j = (lane < KNN) ? idx[pix * KNN + lane] : n;
  float a0 = xb[j], a1 = xb[NP + j], a2 = xb[2*NP + j];
  float r0 = a0 - c0, r1 = a1 - c1, r2 = a2 - c2;
  float g0 = a1*c2 - a2*c1, g1 = a2*c0 - a0*c2, g2 = a0*c1 - a1*c0;
  float h[21][3];
  #pragma unroll
  for (int o = 0; o < 21; o++){
    float w0 = Wf[o*3], w1 = Wf[o*3+1], w2 = Wf[o*3+2];
    float p0 = w0*r0 + w1*c0 + w2*g0;
    float p1 = w0*r1 + w1*c1 + w2*g1;
    float p2 = w0*r2 + w1*c2 + w2*g2;
    float nm = sqrtf(p0*p0 + p1*p1 + p2*p2) + EPSF;
    float f = (nm - mi[2*o]) * mi[2*o+1] / nm;
    p0 *= f; p1 *= f; p2 *= f;
    float v0 = Wd[o*3], v1 = Wd[o*3+1], v2 = Wd[o*3+2];
    float d0 = v0*r0 + v1*c0 + v2*g0;
    float d1 = v0*r1 + v1*c1 + v2*g1;
    float d2 = v0*r2 + v1*c2 + v2*g2;
    float dot = p0*d0 + p1*d1 + p2*d2;
    float dsq = d0*d0 + d1*d1 + d2*d2;
    float t = dot / (dsq + EPSF);
    h[o][0] = (dot >= 0.f) ? p0 : fmaf(-t, d0, p0);
    h[o][1] = (dot >= 0.f) ? p1 : fmaf(-t, d1, p1);
    h[o][2] = (dot >= 0.f) ? p2 : fmaf(-t, d2, p2);
  }
  #pragma unroll
  for (int o = 0; o < 21; o++){
    float q0 = 0.f, q1 = 0.f, q2 = 0.f;
    #pragma unroll
    for (int c = 0; c < 21; c++){
      float wg = Wg[o*21 + c];
      q0 = fmaf(wg, h[c][0], q0); q1 = fmaf(wg, h[c][1], q1); q2 = fmaf(wg, h[c][2], q2);
    }
    float dp = q0*h[o][0] + q1*h[o][1] + q2*h[o][2];
    float m = (lane < KNN) ? dp : -INFINITY;
    #pragma unroll
    for (int s = 32; s > 0; s >>= 1) m = fmaxf(m, __shfl_xor(m, s, 64));
    unsigned long long msk = __ballot(lane < KNN && dp == m);
    int wl = __ffsll(msk) - 1;
    float o0 = __shfl(h[o][0], wl, 64);
    float o1 = __shfl(h[o][1], wl, 64);
    float o2 = __shfl(h[o][2], wl, 64);
    if (lane == 0){
      float* dst = h1 + (size_t)((b*21 + o)*3) * NP + n;
      dst[0] = o0; dst[NP] = o1; dst[2*NP] = o2;
    }
  }
}

// ------- VN layer stats, o-chunked register tiling: block = 1024 px x 8 outputs --------
template<int CIN>
__global__ __launch_bounds__(256) void layer_stats2(const float* __restrict__ hin, const float* __restrict__ Wf,
                                                    double* __restrict__ sums, int Co){
  const int px0 = blockIdx.x * 1024;
  const int b = px0 >> 11;
  const int n0 = (px0 & 2047) + (threadIdx.x << 2);
  const int o0 = blockIdx.y * 8;
  const float* hb = hin + (size_t)b * CIN * 3 * NP + n0;
  float p[8][3][4];
  #pragma unroll
  for (int oo = 0; oo < 8; oo++)
    #pragma unroll
    for (int e = 0; e < 3; e++)
      #pragma unroll
      for (int k = 0; k < 4; k++) p[oo][e][k] = 0.f;
  for (int c = 0; c < CIN; c++){
    float4 hv[3];
    #pragma unroll
    for (int e = 0; e < 3; e++) hv[e] = *(const float4*)&hb[(size_t)(c*3 + e) * NP];
    #pragma unroll
    for (int oo = 0; oo < 8; oo++){
      int o = o0 + oo; if (o >= Co) o = Co - 1;
      float wv = Wf[o*CIN + c];
      #pragma unroll
      for (int e = 0; e < 3; e++){
        p[oo][e][0] = fmaf(wv, hv[e].x, p[oo][e][0]);
        p[oo][e][1] = fmaf(wv, hv[e].y, p[oo][e][1]);
        p[oo][e][2] = fmaf(wv, hv[e].z, p[oo][e][2]);
        p[oo][e][3] = fmaf(wv, hv[e].w, p[oo][e][3]);
      }
    }
  }
  float sl[8], ql[8];
  #pragma unroll
  for (int oo = 0; oo < 8; oo++){
    sl[oo] = 0.f; ql[oo] = 0.f;
    #pragma unroll
    for (int k = 0; k < 4; k++){
      float nm = sqrtf(p[oo][0][k]*p[oo][0][k] + p[oo][1][k]*p[oo][1][k] + p[oo][2][k]*p[oo][2][k]) + EPSF;
      sl[oo] += nm; ql[oo] += nm * nm;
    }
  }
  __shared__ float red[4][16];
  int w = threadIdx.x >> 6;
  #pragma unroll
  for (int oo = 0; oo < 8; oo++){
    float sv = sl[oo], qv = ql[oo];
    #pragma unroll
    for (int st = 1; st < 64; st <<= 1){ sv += __shfl_xor(sv, st, 64); qv += __shfl_xor(qv, st, 64); }
    if ((threadIdx.x & 63) == 0){ red[w][oo] = sv; red[w][8 + oo] = qv; }
  }
  __syncthreads();
  if (threadIdx.x < 16){
    float tot = red[0][threadIdx.x] + red[1][threadIdx.x] + red[2][threadIdx.x] + red[3][threadIdx.x];
    int oo = threadIdx.x & 7, isq = threadIdx.x >> 3;
    int o = o0 + oo;
    if (o < Co) atomicAdd(&sums[2*o + isq], (double)tot);
  }
}

// ------- VN layer apply, o-chunked: block = 256 px x 8 outputs, fp32 out ---------------
template<int CIN>
__global__ __launch_bounds__(256) void layer_apply2(const float* __restrict__ hin, const float* __restrict__ Wf,
    const float* __restrict__ Wd, const float* __restrict__ mi, float* __restrict__ hout, int Co){
  const int px = blockIdx.x * 256 + threadIdx.x;
  const int b = px >> 11, n = px & 2047;
  const int o0 = blockIdx.y * 8;
  const float* hb = hin + (size_t)b * CIN * 3 * NP + n;
  float p[8][3], d[8][3];
  #pragma unroll
  for (int oo = 0; oo < 8; oo++)
    #pragma unroll
    for (int e = 0; e < 3; e++){ p[oo][e] = 0.f; d[oo][e] = 0.f; }
  for (int c = 0; c < CIN; c++){
    float h0 = hb[(size_t)(c*3 + 0) * NP];
    float h1 = hb[(size_t)(c*3 + 1) * NP];
    float h2 = hb[(size_t)(c*3 + 2) * NP];
    #pragma unroll
    for (int oo = 0; oo < 8; oo++){
      int o = o0 + oo; if (o >= Co) o = Co - 1;
      float wf = Wf[o*CIN + c], wd = Wd[o*CIN + c];
      p[oo][0] = fmaf(wf, h0, p[oo][0]); p[oo][1] = fmaf(wf, h1, p[oo][1]); p[oo][2] = fmaf(wf, h2, p[oo][2]);
      d[oo][0] = fmaf(wd, h0, d[oo][0]); d[oo][1] = fmaf(wd, h1, d[oo][1]); d[oo][2] = fmaf(wd, h2, d[oo][2]);
    }
  }
  #pragma unroll
  for (int oo = 0; oo < 8; oo++){
    int o = o0 + oo;
    if (o < Co){
      float nm = sqrtf(p[oo][0]*p[oo][0] + p[oo][1]*p[oo][1] + p[oo][2]*p[oo][2]) + EPSF;
      float f = (nm - mi[2*o]) * mi[2*o+1] / nm;
      float p0 = p[oo][0]*f, p1 = p[oo][1]*f, p2 = p[oo][2]*f;
      float dot = p0*d[oo][0] + p1*d[oo][1] + p2*d[oo][2];
      float dsq = d[oo][0]*d[oo][0] + d[oo][1]*d[oo][1] + d[oo][2]*d[oo][2];
      float t = dot / (dsq + EPSF);
      float r0 = (dot >= 0.f) ? p0 : fmaf(-t, d[oo][0], p0);
      float r1 = (dot >= 0.f) ? p1 : fmaf(-t, d[oo][1], p1);
      float r2 = (dot >= 0.f) ? p2 : fmaf(-t, d[oo][2], p2);
      float* dst = hout + (size_t)((b*Co + o)*3) * NP + n;
      dst[0] = r0; dst[NP] = r1; dst[2*NP] = r2;
    }
  }
}

// ------- last VN layer (42->341): o-chunked apply + k-packed bf16 hi/lo output ---------
// Hk layout: [b][e][kb=0..47][n][j=0..7]; grid y=44 covers kb 0..43 (zero-padded tail)
__global__ __launch_bounds__(256) void layer_apply_l3v2(const float* __restrict__ hin, const float* __restrict__ Wf,
    const float* __restrict__ Wd, const float* __restrict__ mi,
    unsigned short* __restrict__ Hkh, unsigned short* __restrict__ Hkl){
  const int px = blockIdx.x * 256 + threadIdx.x;
  const int b = px >> 11, n = px & 2047;
  const int o0 = blockIdx.y * 8;
  const float* hb = hin + (size_t)b * 42 * 3 * NP + n;
  float r[8][3];
  #pragma unroll
  for (int oo = 0; oo < 8; oo++)
    #pragma unroll
    for (int e = 0; e < 3; e++) r[oo][e] = 0.f;
  if (o0 < 341){
    float p[8][3], d[8][3];
    #pragma unroll
    for (int oo = 0; oo < 8; oo++)
      #pragma unroll
      for (int e = 0; e < 3; e++){ p[oo][e] = 0.f; d[oo][e] = 0.f; }
    for (int c = 0; c < 42; c++){
      float h0 = hb[(size_t)(c*3 + 0) * NP];
      float h1 = hb[(size_t)(c*3 + 1) * NP];
      float h2 = hb[(size_t)(c*3 + 2) * NP];
      #pragma unroll
      for (int oo = 0; oo < 8; oo++){
        int o = o0 + oo; if (o >= 341) o = 340;
        float wf = Wf[o*42 + c], wd = Wd[o*42 + c];
        p[oo][0] = fmaf(wf, h0, p[oo][0]); p[oo][1] = fmaf(wf, h1, p[oo][1]); p[oo][2] = fmaf(wf, h2, p[oo][2]);
        d[oo][0] = fmaf(wd, h0, d[oo][0]); d[oo][1] = fmaf(wd, h1, d[oo][1]); d[oo][2] = fmaf(wd, h2, d[oo][2]);
      }
    }
    #pragma unroll
    for (int oo = 0; oo < 8; oo++){
      int o = o0 + oo;
      if (o < 341){
        float nm = sqrtf(p[oo][0]*p[oo][0] + p[oo][1]*p[oo][1] + p[oo][2]*p[oo][2]) + EPSF;
        float f = (nm - mi[2*o]) * mi[2*o+1] / nm;
        float p0 = p[oo][0]*f, p1 = p[oo][1]*f, p2 = p[oo][2]*f;
        float dot = p0*d[oo][0] + p1*d[oo][1] + p2*d[oo][2];
        float dsq = d[oo][0]*d[oo][0] + d[oo][1]*d[oo][1] + d[oo][2]*d[oo][2];
        float t = dot / (dsq + EPSF);
        r[oo][0] = (dot >= 0.f) ? p0 : fmaf(-t, d[oo][0], p0);
        r[oo][1] = (dot >= 0.f) ? p1 : fmaf(-t, d[oo][1], p1);
        r[oo][2] = (dot >= 0.f) ? p2 : fmaf(-t, d[oo][2], p2);
      }
    }
  }
  #pragma unroll
  for (int e = 0; e < 3; e++){
    unsigned ph[4], pl[4];
    #pragma unroll
    for (int oo = 0; oo < 8; oo++){
      unsigned short hh, ll;
      bsplit(r[oo][e], hh, ll);
      if (!(oo & 1)){ ph[oo>>1] = hh; pl[oo>>1] = ll; }
      else { ph[oo>>1] |= ((unsigned)hh) << 16; pl[oo>>1] |= ((unsigned)ll) << 16; }
    }
    size_t base = ((((size_t)(b*3 + e))*48 + blockIdx.y) * 2048 + n) * 8;
    *(uint4*)(Hkh + base) = make_uint4(ph[0], ph[1], ph[2], ph[3]);
    *(uint4*)(Hkl + base) = make_uint4(pl[0], pl[1], pl[2], pl[3]);
  }
}

__global__ void finalize_stats(const double* __restrict__ sums, float* __restrict__ mi, int Co, double invM){
  int o = blockIdx.x * 64 + threadIdx.x;
  if (o >= Co) return;
  double m = sums[2*o] * invM;
  double v = sums[2*o+1] * invM - m * m;
  if (v < 0.0) v = 0.0;
  mi[2*o] = (float)m;
  mi[2*o+1] = (float)(1.0 / sqrt(v + (double)BNEPS));
}

// ------- split W_pool into k-packed bf16 hi/lo: Wk[cb=0..43][o=0..383][j=0..7] ---------
__global__ __launch_bounds__(256) void wk_kernel(const float* __restrict__ Wp,
    unsigned short* __restrict__ Wkh, unsigned short* __restrict__ Wkl){
  int t = blockIdx.x * 256 + threadIdx.x;
  if (t >= 44*384*8) return;
  int j = t & 7, o = (t >> 3) % 384, cb = t / (384*8);
  int c = cb*8 + j;
  float v = (c < 341 && o < 341) ? Wp[o*341 + c] : 0.f;
  unsigned short h, l;
  bsplit(v, h, l);
  Wkh[t] = h; Wkl[t] = l;
}

// ------------- pool over N via split-bf16 MFMA: D = Wpool @ H; dot; argmax -------------
__global__ __launch_bounds__(256) void pool_mfma(const unsigned short* __restrict__ Wkh,
    const unsigned short* __restrict__ Wkl, const unsigned short* __restrict__ Hkh,
    const unsigned short* __restrict__ Hkl, unsigned long long* __restrict__ packed){
  __shared__ unsigned short sB[2][2][4][64][8];   // [buf][hi/lo][kb][n][j] = 16 KB
  const int b = blockIdx.z, o0 = blockIdx.y * 128, n0 = blockIdx.x * 64;
  const int t = threadIdx.x, w = t >> 6, l = t & 63;
  const int wo = o0 + w * 32;
  const int r = l & 15, g = l >> 4;
  const int skb = t >> 6, sn = t & 63;
  const int ktw = wo >> 5;

  f32x4 acc[2][4], dotv[2][4], hval[2][4];
  #pragma unroll
  for (int s = 0; s < 2; s++)
    #pragma unroll
    for (int nt = 0; nt < 4; nt++){ dotv[s][nt] = (f32x4)0.f; hval[s][nt] = (f32x4)0.f; }

  auto gsrc = [&](const unsigned short* base, int e, int kt) -> const uint4* {
    return (const uint4*)(base + ((((size_t)(b*3 + e))*48 + (size_t)(kt*4 + skb)) * 2048 + n0 + sn) * 8);
  };

  uint4 rg[2];
  rg[0] = *gsrc(Hkh, 0, 0);
  rg[1] = *gsrc(Hkl, 0, 0);

  for (int ek = 0; ek < 33; ek++){
    const int e = ek / 11, kt = ek - e*11, buf = ek & 1;
    *(uint4*)&sB[buf][0][skb][sn][0] = rg[0];
    *(uint4*)&sB[buf][1][skb][sn][0] = rg[1];
    __syncthreads();
    if (ek < 32){
      int e2 = (ek+1) / 11, kt2 = (ek+1) - e2*11;
      rg[0] = *gsrc(Hkh, e2, kt2);
      rg[1] = *gsrc(Hkl, e2, kt2);
    }
    if (kt == 0){
      #pragma unroll
      for (int s = 0; s < 2; s++)
        #pragma unroll
        for (int nt = 0; nt < 4; nt++) acc[s][nt] = (f32x4)0.f;
    }
    short8 ah[2], al[2];
    #pragma unroll
    for (int s = 0; s < 2; s++){
      size_t aoff = (((size_t)(kt*4 + g)) * 384 + (wo + s*16 + r)) * 8;
      ah[s] = *(const short8*)(Wkh + aoff);
      al[s] = *(const short8*)(Wkl + aoff);
    }
    #pragma unroll
    for (int nt = 0; nt < 4; nt++){
      short8 bh = *(const short8*)&sB[buf][0][g][nt*16 + r][0];
      short8 bl = *(const short8*)&sB[buf][1][g][nt*16 + r][0];
      #pragma unroll
      for (int s = 0; s < 2; s++){
        acc[s][nt] = __builtin_amdgcn_mfma_f32_16x16x32_bf16(ah[s], bh, acc[s][nt], 0, 0, 0);
        acc[s][nt] = __builtin_amdgcn_mfma_f32_16x16x32_bf16(ah[s], bl, acc[s][nt], 0, 0, 0);
        acc[s][nt] = __builtin_amdgcn_mfma_f32_16x16x32_bf16(al[s], bh, acc[s][nt], 0, 0, 0);
      }
    }
    if (kt == ktw){
      #pragma unroll
      for (int s = 0; s < 2; s++){
        #pragma unroll
        for (int jj = 0; jj < 4; jj++){
          int oin = s*16 + g*4 + jj;
          #pragma unroll
          for (int nt = 0; nt < 4; nt++){
            hval[s][nt][jj] = bf2f(sB[buf][0][oin>>3][nt*16 + r][oin&7])
                            + bf2f(sB[buf][1][oin>>3][nt*16 + r][oin&7]);
          }
        }
      }
    }
    __syncthreads();
    if (kt == 10){
      #pragma unroll
      for (int s = 0; s < 2; s++)
        #pragma unroll
        for (int nt = 0; nt < 4; nt++)
          #pragma unroll
          for (int jj = 0; jj < 4; jj++)
            dotv[s][nt][jj] += acc[s][nt][jj] * hval[s][nt][jj];
    }
  }
  #pragma unroll
  for (int s = 0; s < 2; s++){
    #pragma unroll
    for (int j = 0; j < 4; j++){
      int o = wo + s*16 + g*4 + j;
      unsigned long long best = 0;
      #pragma unroll
      for (int nt = 0; nt < 4; nt++){
        int n = n0 + nt*16 + r;
        unsigned long long pk = ((unsigned long long)ordf(dotv[s][nt][j]) << 32) | (unsigned)(2047 - n);
        if (pk > best) best = pk;
      }
      #pragma unroll
      for (int st = 1; st < 16; st <<= 1){
        unsigned long long ob = __shfl_xor(best, st, 64);
        if (ob > best) best = ob;
      }
      if (r == 0 && o < 341) atomicMax(&packed[b*341 + o], best);
    }
  }
}

__global__ void pool_gather(const unsigned long long* __restrict__ packed,
                            const unsigned short* __restrict__ Hkh, const unsigned short* __restrict__ Hkl,
                            float* __restrict__ pooled){
  int t = blockIdx.x * 256 + threadIdx.x;
  if (t >= BATCH * 341) return;
  int n = 2047 - (int)(packed[t] & 0xffffffffu);
  int b = t / 341, o = t % 341;
  #pragma unroll
  for (int e = 0; e < 3; e++){
    size_t hb = ((((size_t)(b*3 + e))*48 + (o >> 3)) * 2048 + n) * 8 + (o & 7);
    pooled[t*3 + e] = bf2f(Hkh[hb]) + bf2f(Hkl[hb]);
  }
}

// -------- fully-connected VN layer (B=8 pixels, per-channel bn over B) -----------------
__global__ __launch_bounds__(64) void flayer(const float* __restrict__ in, const float* __restrict__ Wf,
    const float* __restrict__ Wd, float* __restrict__ out, int Cin, int Co){
  int o = blockIdx.x, lane = threadIdx.x;
  float pv[24], dv[24];
  #pragma unroll
  for (int be = 0; be < 24; be++){ pv[be] = 0.f; dv[be] = 0.f; }
  for (int c = lane; c < Cin; c += 64){
    float wf = Wf[o*Cin + c], wd = Wd[o*Cin + c];
    #pragma unroll
    for (int bb = 0; bb < 8; bb++){
      #pragma unroll
      for (int e = 0; e < 3; e++){
        float hv = in[(bb*Cin + c)*3 + e];
        pv[bb*3+e] = fmaf(wf, hv, pv[bb*3+e]);
        dv[bb*3+e] = fmaf(wd, hv, dv[bb*3+e]);
      }
    }
  }
  #pragma unroll
  for (int be = 0; be < 24; be++){
    #pragma unroll
    for (int st = 1; st < 64; st <<= 1){
      pv[be] += __shfl_xor(pv[be], st, 64);
      dv[be] += __shfl_xor(dv[be], st, 64);
    }
  }
  float nm[8], dotb[8], dsqb[8];
  float mean = 0.f;
  #pragma unroll
  for (int bb = 0; bb < 8; bb++){
    nm[bb] = sqrtf(pv[bb*3]*pv[bb*3] + pv[bb*3+1]*pv[bb*3+1] + pv[bb*3+2]*pv[bb*3+2]) + EPSF;
    mean += nm[bb];
  }
  mean *= 0.125f;
  float var = 0.f;
  #pragma unroll
  for (int bb = 0; bb < 8; bb++){ float dvv = nm[bb] - mean; var += dvv * dvv; }
  var *= 0.125f;
  float istd = 1.f / sqrtf(var + BNEPS);
  #pragma unroll
  for (int bb = 0; bb < 8; bb++){
    float f = (nm[bb] - mean) * istd / nm[bb];
    dotb[bb] = f * (pv[bb*3]*dv[bb*3] + pv[bb*3+1]*dv[bb*3+1] + pv[bb*3+2]*dv[bb*3+2]);
    dsqb[bb] = dv[bb*3]*dv[bb*3] + dv[bb*3+1]*dv[bb*3+1] + dv[bb*3+2]*dv[bb*3+2];
  }
  #pragma unroll
  for (int be = 0; be < 24; be++){
    if (lane == be){
      int bb = be / 3;
      float f = (nm[bb] - mean) * istd / nm[bb];
      float pe = pv[be] * f;
      float t = dotb[bb] / (dsqb[bb] + EPSF);
      float res = (dotb[bb] >= 0.f) ? pe : fmaf(-t, dv[be], pe);
      out[(bb*Co + o)*3 + (be % 3)] = res;
    }
  }
}

__global__ void final_lin(const float* __restrict__ in, const float* __restrict__ W, float* __restrict__ out){
  int t = threadIdx.x;
  if (t >= 72) return;
  int b = t / 9, o = (t % 9) / 3, e = t % 3;
  float s = 0.f;
  for (int c = 0; c < 85; c++) s = fmaf(W[o*85 + c], in[(b*85 + c)*3 + e], s);
  out[t] = s;
}

// --------------------------------- launcher -------------------------------------------
extern "C" void kernel_launch(void* const* d_in, const int* in_sizes, int n_in,
                              void* d_out, int out_size, void* d_ws, size_t ws_size,
                              hipStream_t stream){
  const float* x   = (const float*)d_in[0];
  const float* Wpf = (const float*)d_in[1];
  const float* Wpd = (const float*)d_in[2];
  const float* Wg  = (const float*)d_in[3];
  const float* W1f = (const float*)d_in[4];
  const float* W1d = (const float*)d_in[5];
  const float* W2f = (const float*)d_in[6];
  const float* W2d = (const float*)d_in[7];
  const float* W3f = (const float*)d_in[8];
  const float* W3d = (const float*)d_in[9];
  const float* Wpool = (const float*)d_in[10];
  const float* Wf1f = (const float*)d_in[11];
  const float* Wf1d = (const float*)d_in[12];
  const float* Wf2f = (const float*)d_in[13];
  const float* Wf2d = (const float*)d_in[14];
  const float* Wf3  = (const float*)d_in[15];
  float* out = (float*)d_out;

  char* ws = (char*)d_ws;
  size_t off = 0;
  int*   idx = (int*)(ws + off);              off += (size_t)BATCH*NP*KNN*4;
  float* h1  = (float*)(ws + off);            off += (size_t)BATCH*21*3*NP*4;
  float* h2  = (float*)(ws + off);            off += (size_t)BATCH*21*3*NP*4;
  float* h3  = (float*)(ws + off);            off += (size_t)BATCH*42*3*NP*4;
  unsigned short* Hkh = (unsigned short*)(ws + off); off += (size_t)BATCH*3*48*NP*8*2;
  unsigned short* Hkl = (unsigned short*)(ws + off); off += (size_t)BATCH*3*48*NP*8*2;
  unsigned short* Wkh = (unsigned short*)(ws + off); off += (size_t)44*384*8*2;
  unsigned short* Wkl = (unsigned short*)(ws + off); off += (size_t)44*384*8*2;
  char*  zbase = ws + off;
  double* sums_gf = (double*)(ws + off);      off += 8192;
  double* sums_l1 = (double*)(ws + off);      off += 8192;
  double* sums_l2 = (double*)(ws + off);      off += 8192;
  double* sums_l3 = (double*)(ws + off);      off += 8192;
  unsigned long long* packed = (unsigned long long*)(ws + off); off += 24576;
  size_t zbytes = (ws + off) - zbase;
  float* mi_gf = (float*)(ws + off);          off += 1024;
  float* mi_l1 = (float*)(ws + off);          off += 1024;
  float* mi_l2 = (float*)(ws + off);          off += 1024;
  float* mi_l3 = (float*)(ws + off);          off += 4096;
  float* pooled = (float*)(ws + off);         off += (size_t)BATCH*341*3*4 + 32;
  float* h5 = (float*)(ws + off);             off += (size_t)BATCH*170*3*4 + 32;
  float* h6 = (float*)(ws + off);             off += (size_t)BATCH*85*3*4 + 32;

  hipMemsetAsync(zbase, 0, zbytes, stream);

  knn_kernel<<<BATCH*NP/4, 256, 0, stream>>>(x, idx);
  wk_kernel<<<(44*384*8 + 255)/256, 256, 0, stream>>>(Wpool, Wkh, Wkl);

  gf_stats<<<256, 256, 0, stream>>>(x, idx, Wpf, sums_gf);
  finalize_stats<<<1, 64, 0, stream>>>(sums_gf, mi_gf, 21, 1.0 / (double)(BATCH*NP*KNN));
  gf_applypool<<<BATCH*NP/4, 256, 0, stream>>>(x, idx, Wpf, Wpd, Wg, mi_gf, h1);

  layer_stats2<21><<<dim3(16,3), 256, 0, stream>>>(h1, W1f, sums_l1, 21);
  finalize_stats<<<1, 64, 0, stream>>>(sums_l1, mi_l1, 21, 1.0 / (double)(BATCH*NP));
  layer_apply2<21><<<dim3(64,3), 256, 0, stream>>>(h1, W1f, W1d, mi_l1, h2, 21);

  layer_stats2<21><<<dim3(16,6), 256, 0, stream>>>(h2, W2f, sums_l2, 42);
  finalize_stats<<<1, 64, 0, stream>>>(sums_l2, mi_l2, 42, 1.0 / (double)(BATCH*NP));
  layer_apply2<21><<<dim3(64,6), 256, 0, stream>>>(h2, W2f, W2d, mi_l2, h3, 42);

  layer_stats2<42><<<dim3(16,43), 256, 0, stream>>>(h3, W3f, sums_l3, 341);
  finalize_stats<<<6, 64, 0, stream>>>(sums_l3, mi_l3, 341, 1.0 / (double)(BATCH*NP));
  layer_apply_l3v2<<<dim3(64,44), 256, 0, stream>>>(h3, W3f, W3d, mi_l3, Hkh, Hkl);

  pool_mfma<<<dim3(32, 3, BATCH), 256, 0, stream>>>(Wkh, Wkl, Hkh, Hkl, packed);
  pool_gather<<<(BATCH*341 + 255)/256, 256, 0, stream>>>(packed, Hkh, Hkl, pooled);

  flayer<<<170, 64, 0, stream>>>(pooled, Wf1f, Wf1d, h5, 341, 170);
  flayer<<<85, 64, 0, stream>>>(h5, Wf2f, Wf2d, h6, 170, 85);
  final_lin<<<1, 128, 0, stream>>>(h6, Wf3, out);
}

// Round 6
// 533.571 us; speedup vs baseline: 2.2287x; 1.0253x over previous
//
#include <hip/hip_runtime.h>

#define NP 2048
#define BATCH 8
#define KNN 40
#define EPSF 1e-6f
#define BNEPS 1e-5f

typedef __attribute__((ext_vector_type(8))) short short8;
typedef __attribute__((ext_vector_type(4))) float f32x4;

__device__ __forceinline__ unsigned ordf(float v){
  unsigned u = __float_as_uint(v);
  return (u & 0x80000000u) ? ~u : (u | 0x80000000u);
}

// split fp32 -> bf16 hi (RNE) + bf16 lo (RNE of residual)
__device__ __forceinline__ void bsplit(float v, unsigned short &h, unsigned short &l){
  unsigned u = __float_as_uint(v);
  unsigned hu = (u + 0x7fffu + ((u >> 16) & 1u)) >> 16;
  h = (unsigned short)hu;
  float r = v - __uint_as_float(hu << 16);
  unsigned u2 = __float_as_uint(r);
  l = (unsigned short)((u2 + 0x7fffu + ((u2 >> 16) & 1u)) >> 16);
}

__device__ __forceinline__ float bf2f(unsigned short h){
  return __uint_as_float(((unsigned)h) << 16);
}

// ---------------- KNN: exact top-40 (nearest incl. self), tie -> lowest index ----------
// One wave per (b,i). LDS float4 (x,y,z,|x|^2); per-lane top-4 cache; 32-bit pop reduce.
__global__ __launch_bounds__(256) void knn_kernel(const float* __restrict__ x, int* __restrict__ idx){
  __shared__ float4 sP[NP];   // 32 KB
  int tid = threadIdx.x;
  int w = tid >> 6, lane = tid & 63;
  int row = blockIdx.x * 4 + w;
  int b = row >> 11, i = row & 2047;
  const float* xb = x + b * 3 * NP;
  for (int t = tid; t < NP; t += 256){
    float a = xb[t], c = xb[NP + t], d = xb[2*NP + t];
    float xx = __fadd_rn(__fadd_rn(__fmul_rn(a,a), __fmul_rn(c,c)), __fmul_rn(d,d));
    sP[t] = make_float4(a, c, d, xx);
  }
  __syncthreads();
  float4 pi = sP[i];
  const float4* lp = &sP[lane];
  unsigned long long s0 = 0, s1 = 0, s2 = 0, s3 = 0;
  #pragma unroll
  for (int m = 0; m < 32; m++){
    float4 pj = lp[m * 64];
    float dot = __fadd_rn(__fadd_rn(__fmul_rn(pi.x, pj.x), __fmul_rn(pi.y, pj.y)), __fmul_rn(pi.z, pj.z));
    float v = __fsub_rn(__fsub_rn(-pi.w, __fmul_rn(-2.f, dot)), pj.w);
    unsigned long long pk = ((unsigned long long)ordf(v) << 32) | (unsigned)(2047 - (m*64 + lane));
    if (pk > s3){
      if (pk > s2){ s3 = s2; if (pk > s1){ s2 = s1; if (pk > s0){ s1 = s0; s0 = pk; } else s1 = pk; } else s2 = pk; }
      else s3 = pk;
    }
  }
  unsigned myout = 0;
  unsigned long long lastPop = ~0ull;
  for (int kk = 0; kk < KNN; kk++){
    unsigned hv = (unsigned)(s0 >> 32);
    unsigned vm = hv;
    #pragma unroll
    for (int st = 32; st > 0; st >>= 1){
      unsigned o = (unsigned)__shfl_xor((int)vm, st, 64);
      vm = (o > vm) ? o : vm;
    }
    bool cand = (hv == vm);
    unsigned long long msk = __ballot(cand);
    unsigned lo;
    if (__popcll(msk) == 1){
      int wl = __ffsll((unsigned long long)msk) - 1;
      lo = (unsigned)__shfl((int)(unsigned)s0, wl, 64);
    } else {
      unsigned cl = cand ? (unsigned)s0 : 0u;
      #pragma unroll
      for (int st = 32; st > 0; st >>= 1){
        unsigned o = (unsigned)__shfl_xor((int)cl, st, 64);
        cl = (o > cl) ? o : cl;
      }
      lo = cl;
    }
    if (lane == kk) myout = lo;
    if (cand && (unsigned)s0 == lo){
      lastPop = s0;
      s0 = s1; s1 = s2; s2 = s3; s3 = 0;
      if (s0 == 0){
        unsigned long long best = 0;
        #pragma unroll
        for (int m = 0; m < 32; m++){
          float4 pj = lp[m * 64];
          float dot = __fadd_rn(__fadd_rn(__fmul_rn(pi.x, pj.x), __fmul_rn(pi.y, pj.y)), __fmul_rn(pi.z, pj.z));
          float v = __fsub_rn(__fsub_rn(-pi.w, __fmul_rn(-2.f, dot)), pj.w);
          unsigned long long pk = ((unsigned long long)ordf(v) << 32) | (unsigned)(2047 - (m*64 + lane));
          if (pk < lastPop && pk > best) best = pk;
        }
        s0 = best;
      }
    }
  }
  if (lane < KNN) idx[row * KNN + lane] = 2047 - (int)myout;
}

// ------------- graph-feature layer: stats pass (p-norm sums per channel, 21 ch) --------
__global__ __launch_bounds__(256) void gf_stats(const float* __restrict__ x, const int* __restrict__ idx,
                                                const float* __restrict__ Wf, double* __restrict__ sums){
  int tid0 = blockIdx.x * 256 + threadIdx.x;
  float s[21], q[21];
  #pragma unroll
  for (int o = 0; o < 21; o++){ s[o] = 0.f; q[o] = 0.f; }
  for (int pix = tid0; pix < BATCH * NP * KNN; pix += 256 * 256){
    int rem = pix / KNN;
    int n = rem & 2047, b = rem >> 11;
    int j = idx[pix];
    const float* xb = x + b * 3 * NP;
    float c0 = xb[n], c1 = xb[NP + n], c2 = xb[2*NP + n];
    float a0 = xb[j], a1 = xb[NP + j], a2 = xb[2*NP + j];
    float r0 = a0 - c0, r1 = a1 - c1, r2 = a2 - c2;
    float g0 = a1*c2 - a2*c1, g1 = a2*c0 - a0*c2, g2 = a0*c1 - a1*c0;
    #pragma unroll
    for (int o = 0; o < 21; o++){
      float w0 = Wf[o*3], w1 = Wf[o*3+1], w2 = Wf[o*3+2];
      float p0 = w0*r0 + w1*c0 + w2*g0;
      float p1 = w0*r1 + w1*c1 + w2*g1;
      float p2 = w0*r2 + w1*c2 + w2*g2;
      float nm = sqrtf(p0*p0 + p1*p1 + p2*p2) + EPSF;
      s[o] += nm; q[o] += nm * nm;
    }
  }
  __shared__ float bs[4][42];
  int w = threadIdx.x >> 6;
  #pragma unroll
  for (int o = 0; o < 21; o++){
    float a = s[o], bb = q[o];
    #pragma unroll
    for (int st = 1; st < 64; st <<= 1){ a += __shfl_xor(a, st, 64); bb += __shfl_xor(bb, st, 64); }
    if ((threadIdx.x & 63) == 0){ bs[w][o] = a; bs[w][21 + o] = bb; }
  }
  __syncthreads();
  if (threadIdx.x < 42){
    float tot = bs[0][threadIdx.x] + bs[1][threadIdx.x] + bs[2][threadIdx.x] + bs[3][threadIdx.x];
    int o = threadIdx.x % 21, sq = threadIdx.x / 21;
    atomicAdd(&sums[2*o + sq], (double)tot);
  }
}

// -------- graph-feature layer: apply bn+lrelu, then max-pool over K (fused) ------------
__global__ __launch_bounds__(256) void gf_applypool(const float* __restrict__ x, const int* __restrict__ idx,
    const float* __restrict__ Wf, const float* __restrict__ Wd, const float* __restrict__ Wg,
    const float* __restrict__ mi, float* __restrict__ h1){
  int w = threadIdx.x >> 6, lane = threadIdx.x & 63;
  int pix = blockIdx.x * 4 + w;
  int n = pix & 2047, b = pix >> 11;
  const float* xb = x + b * 3 * NP;
  float c0 = xb[n], c1 = xb[NP + n], c2 = xb[2*NP + n];
  int j = (lane < KNN) ? idx[pix * KNN + lane] : n;
  float a0 = xb[j], a1 = xb[NP + j], a2 = xb[2*NP + j];
  float r0 = a0 - c0, r1 = a1 - c1, r2 = a2 - c2;
  float g0 = a1*c2 - a2*c1, g1 = a2*c0 - a0*c2, g2 = a0*c1 - a1*c0;
  float h[21][3];
  #pragma unroll
  for (int o = 0; o < 21; o++){
    float w0 = Wf[o*3], w1 = Wf[o*3+1], w2 = Wf[o*3+2];
    float p0 = w0*r0 + w1*c0 + w2*g0;
    float p1 = w0*r1 + w1*c1 + w2*g1;
    float p2 = w0*r2 + w1*c2 + w2*g2;
    float nm = sqrtf(p0*p0 + p1*p1 + p2*p2) + EPSF;
    float f = (nm - mi[2*o]) * mi[2*o+1] / nm;
    p0 *= f; p1 *= f; p2 *= f;
    float v0 = Wd[o*3], v1 = Wd[o*3+1], v2 = Wd[o*3+2];
    float d0 = v0*r0 + v1*c0 + v2*g0;
    float d1 = v0*r1 + v1*c1 + v2*g1;
    float d2 = v0*r2 + v1*c2 + v2*g2;
    float dot = p0*d0 + p1*d1 + p2*d2;
    float dsq = d0*d0 + d1*d1 + d2*d2;
    float t = dot / (dsq + EPSF);
    h[o][0] = (dot >= 0.f) ? p0 : fmaf(-t, d0, p0);
    h[o][1] = (dot >= 0.f) ? p1 : fmaf(-t, d1, p1);
    h[o][2] = (dot >= 0.f) ? p2 : fmaf(-t, d2, p2);
  }
  #pragma unroll
  for (int o = 0; o < 21; o++){
    float q0 = 0.f, q1 = 0.f, q2 = 0.f;
    #pragma unroll
    for (int c = 0; c < 21; c++){
      float wg = Wg[o*21 + c];
      q0 = fmaf(wg, h[c][0], q0); q1 = fmaf(wg, h[c][1], q1); q2 = fmaf(wg, h[c][2], q2);
    }
    float dp = q0*h[o][0] + q1*h[o][1] + q2*h[o][2];
    float m = (lane < KNN) ? dp : -INFINITY;
    #pragma unroll
    for (int s = 32; s > 0; s >>= 1) m = fmaxf(m, __shfl_xor(m, s, 64));
    unsigned long long msk = __ballot(lane < KNN && dp == m);
    int wl = __ffsll(msk) - 1;
    float o0 = __shfl(h[o][0], wl, 64);
    float o1 = __shfl(h[o][1], wl, 64);
    float o2 = __shfl(h[o][2], wl, 64);
    if (lane == 0){
      float* dst = h1 + (size_t)((b*21 + o)*3) * NP + n;
      dst[0] = o0; dst[NP] = o1; dst[2*NP] = o2;
    }
  }
}

// ------- VN layer stats, o-chunked register tiling: block = 1024 px x 8 outputs --------
template<int CIN>
__global__ __launch_bounds__(256) void layer_stats2(const float* __restrict__ hin, const float* __restrict__ Wf,
                                                    double* __restrict__ sums, int Co){
  const int px0 = blockIdx.x * 1024;
  const int b = px0 >> 11;
  const int n0 = (px0 & 2047) + (threadIdx.x << 2);
  const int o0 = blockIdx.y * 8;
  const float* hb = hin + (size_t)b * CIN * 3 * NP + n0;
  float p[8][3][4];
  #pragma unroll
  for (int oo = 0; oo < 8; oo++)
    #pragma unroll
    for (int e = 0; e < 3; e++)
      #pragma unroll
      for (int k = 0; k < 4; k++) p[oo][e][k] = 0.f;
  for (int c = 0; c < CIN; c++){
    float4 hv[3];
    #pragma unroll
    for (int e = 0; e < 3; e++) hv[e] = *(const float4*)&hb[(size_t)(c*3 + e) * NP];
    #pragma unroll
    for (int oo = 0; oo < 8; oo++){
      int o = o0 + oo; if (o >= Co) o = Co - 1;
      float wv = Wf[o*CIN + c];
      #pragma unroll
      for (int e = 0; e < 3; e++){
        p[oo][e][0] = fmaf(wv, hv[e].x, p[oo][e][0]);
        p[oo][e][1] = fmaf(wv, hv[e].y, p[oo][e][1]);
        p[oo][e][2] = fmaf(wv, hv[e].z, p[oo][e][2]);
        p[oo][e][3] = fmaf(wv, hv[e].w, p[oo][e][3]);
      }
    }
  }
  float sl[8], ql[8];
  #pragma unroll
  for (int oo = 0; oo < 8; oo++){
    sl[oo] = 0.f; ql[oo] = 0.f;
    #pragma unroll
    for (int k = 0; k < 4; k++){
      float nm = sqrtf(p[oo][0][k]*p[oo][0][k] + p[oo][1][k]*p[oo][1][k] + p[oo][2][k]*p[oo][2][k]) + EPSF;
      sl[oo] += nm; ql[oo] += nm * nm;
    }
  }
  __shared__ float red[4][16];
  int w = threadIdx.x >> 6;
  #pragma unroll
  for (int oo = 0; oo < 8; oo++){
    float sv = sl[oo], qv = ql[oo];
    #pragma unroll
    for (int st = 1; st < 64; st <<= 1){ sv += __shfl_xor(sv, st, 64); qv += __shfl_xor(qv, st, 64); }
    if ((threadIdx.x & 63) == 0){ red[w][oo] = sv; red[w][8 + oo] = qv; }
  }
  __syncthreads();
  if (threadIdx.x < 16){
    float tot = red[0][threadIdx.x] + red[1][threadIdx.x] + red[2][threadIdx.x] + red[3][threadIdx.x];
    int oo = threadIdx.x & 7, isq = threadIdx.x >> 3;
    int o = o0 + oo;
    if (o < Co) atomicAdd(&sums[2*o + isq], (double)tot);
  }
}

// ------- VN layer apply, o-chunked: block = 256 px x 8 outputs, fp32 out ---------------
template<int CIN>
__global__ __launch_bounds__(256) void layer_apply2(const float* __restrict__ hin, const float* __restrict__ Wf,
    const float* __restrict__ Wd, const float* __restrict__ mi, float* __restrict__ hout, int Co){
  const int px = blockIdx.x * 256 + threadIdx.x;
  const int b = px >> 11, n = px & 2047;
  const int o0 = blockIdx.y * 8;
  const float* hb = hin + (size_t)b * CIN * 3 * NP + n;
  float p[8][3], d[8][3];
  #pragma unroll
  for (int oo = 0; oo < 8; oo++)
    #pragma unroll
    for (int e = 0; e < 3; e++){ p[oo][e] = 0.f; d[oo][e] = 0.f; }
  for (int c = 0; c < CIN; c++){
    float h0 = hb[(size_t)(c*3 + 0) * NP];
    float h1 = hb[(size_t)(c*3 + 1) * NP];
    float h2 = hb[(size_t)(c*3 + 2) * NP];
    #pragma unroll
    for (int oo = 0; oo < 8; oo++){
      int o = o0 + oo; if (o >= Co) o = Co - 1;
      float wf = Wf[o*CIN + c], wd = Wd[o*CIN + c];
      p[oo][0] = fmaf(wf, h0, p[oo][0]); p[oo][1] = fmaf(wf, h1, p[oo][1]); p[oo][2] = fmaf(wf, h2, p[oo][2]);
      d[oo][0] = fmaf(wd, h0, d[oo][0]); d[oo][1] = fmaf(wd, h1, d[oo][1]); d[oo][2] = fmaf(wd, h2, d[oo][2]);
    }
  }
  #pragma unroll
  for (int oo = 0; oo < 8; oo++){
    int o = o0 + oo;
    if (o < Co){
      float nm = sqrtf(p[oo][0]*p[oo][0] + p[oo][1]*p[oo][1] + p[oo][2]*p[oo][2]) + EPSF;
      float f = (nm - mi[2*o]) * mi[2*o+1] / nm;
      float p0 = p[oo][0]*f, p1 = p[oo][1]*f, p2 = p[oo][2]*f;
      float dot = p0*d[oo][0] + p1*d[oo][1] + p2*d[oo][2];
      float dsq = d[oo][0]*d[oo][0] + d[oo][1]*d[oo][1] + d[oo][2]*d[oo][2];
      float t = dot / (dsq + EPSF);
      float r0 = (dot >= 0.f) ? p0 : fmaf(-t, d[oo][0], p0);
      float r1 = (dot >= 0.f) ? p1 : fmaf(-t, d[oo][1], p1);
      float r2 = (dot >= 0.f) ? p2 : fmaf(-t, d[oo][2], p2);
      float* dst = hout + (size_t)((b*Co + o)*3) * NP + n;
      dst[0] = r0; dst[NP] = r1; dst[2*NP] = r2;
    }
  }
}

// ------- last VN layer (42->341): o-chunked apply + k-packed bf16 hi/lo output ---------
// Hk layout: [b][e][kb=0..47][n][j=0..7]; grid y=44 covers kb 0..43 (zero-padded tail)
__global__ __launch_bounds__(256) void layer_apply_l3v2(const float* __restrict__ hin, const float* __restrict__ Wf,
    const float* __restrict__ Wd, const float* __restrict__ mi,
    unsigned short* __restrict__ Hkh, unsigned short* __restrict__ Hkl){
  const int px = blockIdx.x * 256 + threadIdx.x;
  const int b = px >> 11, n = px & 2047;
  const int o0 = blockIdx.y * 8;
  const float* hb = hin + (size_t)b * 42 * 3 * NP + n;
  float r[8][3];
  #pragma unroll
  for (int oo = 0; oo < 8; oo++)
    #pragma unroll
    for (int e = 0; e < 3; e++) r[oo][e] = 0.f;
  if (o0 < 341){
    float p[8][3], d[8][3];
    #pragma unroll
    for (int oo = 0; oo < 8; oo++)
      #pragma unroll
      for (int e = 0; e < 3; e++){ p[oo][e] = 0.f; d[oo][e] = 0.f; }
    for (int c = 0; c < 42; c++){
      float h0 = hb[(size_t)(c*3 + 0) * NP];
      float h1 = hb[(size_t)(c*3 + 1) * NP];
      float h2 = hb[(size_t)(c*3 + 2) * NP];
      #pragma unroll
      for (int oo = 0; oo < 8; oo++){
        int o = o0 + oo; if (o >= 341) o = 340;
        float wf = Wf[o*42 + c], wd = Wd[o*42 + c];
        p[oo][0] = fmaf(wf, h0, p[oo][0]); p[oo][1] = fmaf(wf, h1, p[oo][1]); p[oo][2] = fmaf(wf, h2, p[oo][2]);
        d[oo][0] = fmaf(wd, h0, d[oo][0]); d[oo][1] = fmaf(wd, h1, d[oo][1]); d[oo][2] = fmaf(wd, h2, d[oo][2]);
      }
    }
    #pragma unroll
    for (int oo = 0; oo < 8; oo++){
      int o = o0 + oo;
      if (o < 341){
        float nm = sqrtf(p[oo][0]*p[oo][0] + p[oo][1]*p[oo][1] + p[oo][2]*p[oo][2]) + EPSF;
        float f = (nm - mi[2*o]) * mi[2*o+1] / nm;
        float p0 = p[oo][0]*f, p1 = p[oo][1]*f, p2 = p[oo][2]*f;
        float dot = p0*d[oo][0] + p1*d[oo][1] + p2*d[oo][2];
        float dsq = d[oo][0]*d[oo][0] + d[oo][1]*d[oo][1] + d[oo][2]*d[oo][2];
        float t = dot / (dsq + EPSF);
        r[oo][0] = (dot >= 0.f) ? p0 : fmaf(-t, d[oo][0], p0);
        r[oo][1] = (dot >= 0.f) ? p1 : fmaf(-t, d[oo][1], p1);
        r[oo][2] = (dot >= 0.f) ? p2 : fmaf(-t, d[oo][2], p2);
      }
    }
  }
  #pragma unroll
  for (int e = 0; e < 3; e++){
    unsigned ph[4], pl[4];
    #pragma unroll
    for (int oo = 0; oo < 8; oo++){
      unsigned short hh, ll;
      bsplit(r[oo][e], hh, ll);
      if (!(oo & 1)){ ph[oo>>1] = hh; pl[oo>>1] = ll; }
      else { ph[oo>>1] |= ((unsigned)hh) << 16; pl[oo>>1] |= ((unsigned)ll) << 16; }
    }
    size_t base = ((((size_t)(b*3 + e))*48 + blockIdx.y) * 2048 + n) * 8;
    *(uint4*)(Hkh + base) = make_uint4(ph[0], ph[1], ph[2], ph[3]);
    *(uint4*)(Hkl + base) = make_uint4(pl[0], pl[1], pl[2], pl[3]);
  }
}

__global__ void finalize_stats(const double* __restrict__ sums, float* __restrict__ mi, int Co, double invM){
  int o = blockIdx.x * 64 + threadIdx.x;
  if (o >= Co) return;
  double m = sums[2*o] * invM;
  double v = sums[2*o+1] * invM - m * m;
  if (v < 0.0) v = 0.0;
  mi[2*o] = (float)m;
  mi[2*o+1] = (float)(1.0 / sqrt(v + (double)BNEPS));
}

// ------- split W_pool into k-packed bf16 hi/lo: Wk[cb=0..43][o=0..383][j=0..7] ---------
__global__ __launch_bounds__(256) void wk_kernel(const float* __restrict__ Wp,
    unsigned short* __restrict__ Wkh, unsigned short* __restrict__ Wkl){
  int t = blockIdx.x * 256 + threadIdx.x;
  if (t >= 44*384*8) return;
  int j = t & 7, o = (t >> 3) % 384, cb = t / (384*8);
  int c = cb*8 + j;
  float v = (c < 341 && o < 341) ? Wp[o*341 + c] : 0.f;
  unsigned short h, l;
  bsplit(v, h, l);
  Wkh[t] = h; Wkl[t] = l;
}

// ------------- pool over N via split-bf16 MFMA: D = Wpool @ H; dot; argmax -------------
__global__ __launch_bounds__(256) void pool_mfma(const unsigned short* __restrict__ Wkh,
    const unsigned short* __restrict__ Wkl, const unsigned short* __restrict__ Hkh,
    const unsigned short* __restrict__ Hkl, unsigned long long* __restrict__ packed){
  __shared__ unsigned short sB[2][2][4][64][8];   // [buf][hi/lo][kb][n][j] = 16 KB
  const int b = blockIdx.z, o0 = blockIdx.y * 128, n0 = blockIdx.x * 64;
  const int t = threadIdx.x, w = t >> 6, l = t & 63;
  const int wo = o0 + w * 32;
  const int r = l & 15, g = l >> 4;
  const int skb = t >> 6, sn = t & 63;
  const int ktw = wo >> 5;

  f32x4 acc[2][4], dotv[2][4], hval[2][4];
  #pragma unroll
  for (int s = 0; s < 2; s++)
    #pragma unroll
    for (int nt = 0; nt < 4; nt++){ dotv[s][nt] = (f32x4)0.f; hval[s][nt] = (f32x4)0.f; }

  auto gsrc = [&](const unsigned short* base, int e, int kt) -> const uint4* {
    return (const uint4*)(base + ((((size_t)(b*3 + e))*48 + (size_t)(kt*4 + skb)) * 2048 + n0 + sn) * 8);
  };

  uint4 rg[2];
  rg[0] = *gsrc(Hkh, 0, 0);
  rg[1] = *gsrc(Hkl, 0, 0);

  for (int ek = 0; ek < 33; ek++){
    const int e = ek / 11, kt = ek - e*11, buf = ek & 1;
    *(uint4*)&sB[buf][0][skb][sn][0] = rg[0];
    *(uint4*)&sB[buf][1][skb][sn][0] = rg[1];
    __syncthreads();
    if (ek < 32){
      int e2 = (ek+1) / 11, kt2 = (ek+1) - e2*11;
      rg[0] = *gsrc(Hkh, e2, kt2);
      rg[1] = *gsrc(Hkl, e2, kt2);
    }
    if (kt == 0){
      #pragma unroll
      for (int s = 0; s < 2; s++)
        #pragma unroll
        for (int nt = 0; nt < 4; nt++) acc[s][nt] = (f32x4)0.f;
    }
    short8 ah[2], al[2];
    #pragma unroll
    for (int s = 0; s < 2; s++){
      size_t aoff = (((size_t)(kt*4 + g)) * 384 + (wo + s*16 + r)) * 8;
      ah[s] = *(const short8*)(Wkh + aoff);
      al[s] = *(const short8*)(Wkl + aoff);
    }
    #pragma unroll
    for (int nt = 0; nt < 4; nt++){
      short8 bh = *(const short8*)&sB[buf][0][g][nt*16 + r][0];
      short8 bl = *(const short8*)&sB[buf][1][g][nt*16 + r][0];
      #pragma unroll
      for (int s = 0; s < 2; s++){
        acc[s][nt] = __builtin_amdgcn_mfma_f32_16x16x32_bf16(ah[s], bh, acc[s][nt], 0, 0, 0);
        acc[s][nt] = __builtin_amdgcn_mfma_f32_16x16x32_bf16(ah[s], bl, acc[s][nt], 0, 0, 0);
        acc[s][nt] = __builtin_amdgcn_mfma_f32_16x16x32_bf16(al[s], bh, acc[s][nt], 0, 0, 0);
      }
    }
    if (kt == ktw){
      #pragma unroll
      for (int s = 0; s < 2; s++){
        #pragma unroll
        for (int jj = 0; jj < 4; jj++){
          int oin = s*16 + g*4 + jj;
          #pragma unroll
          for (int nt = 0; nt < 4; nt++){
            hval[s][nt][jj] = bf2f(sB[buf][0][oin>>3][nt*16 + r][oin&7])
                            + bf2f(sB[buf][1][oin>>3][nt*16 + r][oin&7]);
          }
        }
      }
    }
    __syncthreads();
    if (kt == 10){
      #pragma unroll
      for (int s = 0; s < 2; s++)
        #pragma unroll
        for (int nt = 0; nt < 4; nt++)
          #pragma unroll
          for (int jj = 0; jj < 4; jj++)
            dotv[s][nt][jj] += acc[s][nt][jj] * hval[s][nt][jj];
    }
  }
  #pragma unroll
  for (int s = 0; s < 2; s++){
    #pragma unroll
    for (int j = 0; j < 4; j++){
      int o = wo + s*16 + g*4 + j;
      unsigned long long best = 0;
      #pragma unroll
      for (int nt = 0; nt < 4; nt++){
        int n = n0 + nt*16 + r;
        unsigned long long pk = ((unsigned long long)ordf(dotv[s][nt][j]) << 32) | (unsigned)(2047 - n);
        if (pk > best) best = pk;
      }
      #pragma unroll
      for (int st = 1; st < 16; st <<= 1){
        unsigned long long ob = __shfl_xor(best, st, 64);
        if (ob > best) best = ob;
      }
      if (r == 0 && o < 341) atomicMax(&packed[b*341 + o], best);
    }
  }
}

__global__ void pool_gather(const unsigned long long* __restrict__ packed,
                            const unsigned short* __restrict__ Hkh, const unsigned short* __restrict__ Hkl,
                            float* __restrict__ pooled){
  int t = blockIdx.x * 256 + threadIdx.x;
  if (t >= BATCH * 341) return;
  int n = 2047 - (int)(packed[t] & 0xffffffffu);
  int b = t / 341, o = t % 341;
  #pragma unroll
  for (int e = 0; e < 3; e++){
    size_t hb = ((((size_t)(b*3 + e))*48 + (o >> 3)) * 2048 + n) * 8 + (o & 7);
    pooled[t*3 + e] = bf2f(Hkh[hb]) + bf2f(Hkl[hb]);
  }
}

// -------- fully-connected VN layer (B=8 pixels, per-channel bn over B) -----------------
__global__ __launch_bounds__(64) void flayer(const float* __restrict__ in, const float* __restrict__ Wf,
    const float* __restrict__ Wd, float* __restrict__ out, int Cin, int Co){
  int o = blockIdx.x, lane = threadIdx.x;
  float pv[24], dv[24];
  #pragma unroll
  for (int be = 0; be < 24; be++){ pv[be] = 0.f; dv[be] = 0.f; }
  for (int c = lane; c < Cin; c += 64){
    float wf = Wf[o*Cin + c], wd = Wd[o*Cin + c];
    #pragma unroll
    for (int bb = 0; bb < 8; bb++){
      #pragma unroll
      for (int e = 0; e < 3; e++){
        float hv = in[(bb*Cin + c)*3 + e];
        pv[bb*3+e] = fmaf(wf, hv, pv[bb*3+e]);
        dv[bb*3+e] = fmaf(wd, hv, dv[bb*3+e]);
      }
    }
  }
  #pragma unroll
  for (int be = 0; be < 24; be++){
    #pragma unroll
    for (int st = 1; st < 64; st <<= 1){
      pv[be] += __shfl_xor(pv[be], st, 64);
      dv[be] += __shfl_xor(dv[be], st, 64);
    }
  }
  float nm[8], dotb[8], dsqb[8];
  float mean = 0.f;
  #pragma unroll
  for (int bb = 0; bb < 8; bb++){
    nm[bb] = sqrtf(pv[bb*3]*pv[bb*3] + pv[bb*3+1]*pv[bb*3+1] + pv[bb*3+2]*pv[bb*3+2]) + EPSF;
    mean += nm[bb];
  }
  mean *= 0.125f;
  float var = 0.f;
  #pragma unroll
  for (int bb = 0; bb < 8; bb++){ float dvv = nm[bb] - mean; var += dvv * dvv; }
  var *= 0.125f;
  float istd = 1.f / sqrtf(var + BNEPS);
  #pragma unroll
  for (int bb = 0; bb < 8; bb++){
    float f = (nm[bb] - mean) * istd / nm[bb];
    dotb[bb] = f * (pv[bb*3]*dv[bb*3] + pv[bb*3+1]*dv[bb*3+1] + pv[bb*3+2]*dv[bb*3+2]);
    dsqb[bb] = dv[bb*3]*dv[bb*3] + dv[bb*3+1]*dv[bb*3+1] + dv[bb*3+2]*dv[bb*3+2];
  }
  #pragma unroll
  for (int be = 0; be < 24; be++){
    if (lane == be){
      int bb = be / 3;
      float f = (nm[bb] - mean) * istd / nm[bb];
      float pe = pv[be] * f;
      float t = dotb[bb] / (dsqb[bb] + EPSF);
      float res = (dotb[bb] >= 0.f) ? pe : fmaf(-t, dv[be], pe);
      out[(bb*Co + o)*3 + (be % 3)] = res;
    }
  }
}

__global__ void final_lin(const float* __restrict__ in, const float* __restrict__ W, float* __restrict__ out){
  int t = threadIdx.x;
  if (t >= 72) return;
  int b = t / 9, o = (t % 9) / 3, e = t % 3;
  float s = 0.f;
  for (int c = 0; c < 85; c++) s = fmaf(W[o*85 + c], in[(b*85 + c)*3 + e], s);
  out[t] = s;
}

// --------------------------------- launcher -------------------------------------------
extern "C" void kernel_launch(void* const* d_in, const int* in_sizes, int n_in,
                              void* d_out, int out_size, void* d_ws, size_t ws_size,
                              hipStream_t stream){
  const float* x   = (const float*)d_in[0];
  const float* Wpf = (const float*)d_in[1];
  const float* Wpd = (const float*)d_in[2];
  const float* Wg  = (const float*)d_in[3];
  const float* W1f = (const float*)d_in[4];
  const float* W1d = (const float*)d_in[5];
  const float* W2f = (const float*)d_in[6];
  const float* W2d = (const float*)d_in[7];
  const float* W3f = (const float*)d_in[8];
  const float* W3d = (const float*)d_in[9];
  const float* Wpool = (const float*)d_in[10];
  const float* Wf1f = (const float*)d_in[11];
  const float* Wf1d = (const float*)d_in[12];
  const float* Wf2f = (const float*)d_in[13];
  const float* Wf2d = (const float*)d_in[14];
  const float* Wf3  = (const float*)d_in[15];
  float* out = (float*)d_out;

  char* ws = (char*)d_ws;
  size_t off = 0;
  int*   idx = (int*)(ws + off);              off += (size_t)BATCH*NP*KNN*4;
  float* h1  = (float*)(ws + off);            off += (size_t)BATCH*21*3*NP*4;
  float* h2  = (float*)(ws + off);            off += (size_t)BATCH*21*3*NP*4;
  float* h3  = (float*)(ws + off);            off += (size_t)BATCH*42*3*NP*4;
  unsigned short* Hkh = (unsigned short*)(ws + off); off += (size_t)BATCH*3*48*NP*8*2;
  unsigned short* Hkl = (unsigned short*)(ws + off); off += (size_t)BATCH*3*48*NP*8*2;
  unsigned short* Wkh = (unsigned short*)(ws + off); off += (size_t)44*384*8*2;
  unsigned short* Wkl = (unsigned short*)(ws + off); off += (size_t)44*384*8*2;
  char*  zbase = ws + off;
  double* sums_gf = (double*)(ws + off);      off += 8192;
  double* sums_l1 = (double*)(ws + off);      off += 8192;
  double* sums_l2 = (double*)(ws + off);      off += 8192;
  double* sums_l3 = (double*)(ws + off);      off += 8192;
  unsigned long long* packed = (unsigned long long*)(ws + off); off += 24576;
  size_t zbytes = (ws + off) - zbase;
  float* mi_gf = (float*)(ws + off);          off += 1024;
  float* mi_l1 = (float*)(ws + off);          off += 1024;
  float* mi_l2 = (float*)(ws + off);          off += 1024;
  float* mi_l3 = (float*)(ws + off);          off += 4096;
  float* pooled = (float*)(ws + off);         off += (size_t)BATCH*341*3*4 + 32;
  float* h5 = (float*)(ws + off);             off += (size_t)BATCH*170*3*4 + 32;
  float* h6 = (float*)(ws + off);             off += (size_t)BATCH*85*3*4 + 32;

  hipMemsetAsync(zbase, 0, zbytes, stream);

  knn_kernel<<<BATCH*NP/4, 256, 0, stream>>>(x, idx);
  wk_kernel<<<(44*384*8 + 255)/256, 256, 0, stream>>>(Wpool, Wkh, Wkl);

  gf_stats<<<256, 256, 0, stream>>>(x, idx, Wpf, sums_gf);
  finalize_stats<<<1, 64, 0, stream>>>(sums_gf, mi_gf, 21, 1.0 / (double)(BATCH*NP*KNN));
  gf_applypool<<<BATCH*NP/4, 256, 0, stream>>>(x, idx, Wpf, Wpd, Wg, mi_gf, h1);

  layer_stats2<21><<<dim3(16,3), 256, 0, stream>>>(h1, W1f, sums_l1, 21);
  finalize_stats<<<1, 64, 0, stream>>>(sums_l1, mi_l1, 21, 1.0 / (double)(BATCH*NP));
  layer_apply2<21><<<dim3(64,3), 256, 0, stream>>>(h1, W1f, W1d, mi_l1, h2, 21);

  layer_stats2<21><<<dim3(16,6), 256, 0, stream>>>(h2, W2f, sums_l2, 42);
  finalize_stats<<<1, 64, 0, stream>>>(sums_l2, mi_l2, 42, 1.0 / (double)(BATCH*NP));
  layer_apply2<21><<<dim3(64,6), 256, 0, stream>>>(h2, W2f, W2d, mi_l2, h3, 42);

  layer_stats2<42><<<dim3(16,43), 256, 0, stream>>>(h3, W3f, sums_l3, 341);
  finalize_stats<<<6, 64, 0, stream>>>(sums_l3, mi_l3, 341, 1.0 / (double)(BATCH*NP));
  layer_apply_l3v2<<<dim3(64,44), 256, 0, stream>>>(h3, W3f, W3d, mi_l3, Hkh, Hkl);

  pool_mfma<<<dim3(32, 3, BATCH), 256, 0, stream>>>(Wkh, Wkl, Hkh, Hkl, packed);
  pool_gather<<<(BATCH*341 + 255)/256, 256, 0, stream>>>(packed, Hkh, Hkl, pooled);

  flayer<<<170, 64, 0, stream>>>(pooled, Wf1f, Wf1d, h5, 341, 170);
  flayer<<<85, 64, 0, stream>>>(h5, Wf2f, Wf2d, h6, 170, 85);
  final_lin<<<1, 128, 0, stream>>>(h6, Wf3, out);
}